// Round 11
// baseline (284.103 us; speedup 1.0000x reference)
//
#include <hip/hip_runtime.h>

constexpr int CB = 2, CL = 1024, CD = 1024, CNH = 16, CHD = 64, CHDH = 128, CBN = CB * CNH;

__device__ __forceinline__ float sigf(float x) { return 1.0f / (1.0f + __expf(-x)); }

__device__ __forceinline__ unsigned short f2bf(float x) {
    unsigned u = __float_as_uint(x);
    u += 0x7fffu + ((u >> 16) & 1u);
    return (unsigned short)(u >> 16);
}
__device__ __forceinline__ unsigned pk2(float a, float b) {
    return (unsigned)f2bf(a) | ((unsigned)f2bf(b) << 16);
}
__device__ __forceinline__ unsigned pkus(unsigned short a, unsigned short b) {
    return (unsigned)a | ((unsigned)b << 16);
}
__device__ __forceinline__ float bf2f(unsigned short u) {
    return __uint_as_float(((unsigned)u) << 16);
}

typedef __attribute__((ext_vector_type(8))) short short8v;
typedef __attribute__((ext_vector_type(4))) float f32x4;
#define MFMA16(a, b, c) __builtin_amdgcn_mfma_f32_16x16x32_bf16(a, b, c, 0, 0, 0)

// ---------------------------------------------------------------------------
// Convert x, qw, kw, vw to bf16.
// ---------------------------------------------------------------------------
__global__ __launch_bounds__(256) void tobf_kernel(
    const float* __restrict__ x, const float* __restrict__ qw,
    const float* __restrict__ kw, const float* __restrict__ vw,
    unsigned short* __restrict__ xb, unsigned short* __restrict__ qwb,
    unsigned short* __restrict__ kwb, unsigned short* __restrict__ vwb) {
    int i = blockIdx.x * 256 + threadIdx.x;
    const float* s;
    unsigned short* d;
    int off;
    if (i < 524288) { s = x; d = xb; off = i; }
    else if (i < 786432) { s = qw; d = qwb; off = i - 524288; }
    else if (i < 1048576) { s = kw; d = kwb; off = i - 786432; }
    else { s = vw; d = vwb; off = i - 1048576; }
    float4 v = *(const float4*)(s + (size_t)off * 4);
    *(uint2*)(d + (size_t)off * 4) = make_uint2(pk2(v.x, v.y), pk2(v.z, v.w));
}

// ---------------------------------------------------------------------------
// Convert W1 -> w1bf, W2 -> w2bf, W2^T -> w2tbf (bf16).
// ---------------------------------------------------------------------------
__global__ __launch_bounds__(256) void tobf2_kernel(
    const float* __restrict__ W1, const float* __restrict__ W2,
    unsigned short* __restrict__ w1b, unsigned short* __restrict__ w2b,
    unsigned short* __restrict__ w2t) {
    int i = blockIdx.x * 256 + threadIdx.x;  // 0..196607
    if (i < 65536) {
        size_t e = (size_t)i * 4;
        float4 v = *(const float4*)(W1 + e);
        *(uint2*)(w1b + e) = make_uint2(pk2(v.x, v.y), pk2(v.z, v.w));
    } else if (i < 131072) {
        size_t e = (size_t)(i - 65536) * 4;
        float4 v = *(const float4*)(W2 + e);
        *(uint2*)(w2b + e) = make_uint2(pk2(v.x, v.y), pk2(v.z, v.w));
    } else {
        size_t e = (size_t)(i - 131072) * 4;
        int bn = (int)(e >> 13), rem = (int)(e & 8191);
        int h = rem >> 6, d0 = rem & 63;
        const float* src = W2 + (size_t)bn * CHD * CHDH;
        float a = src[(d0 + 0) * CHDH + h], b = src[(d0 + 1) * CHDH + h];
        float c = src[(d0 + 2) * CHDH + h], dd = src[(d0 + 3) * CHDH + h];
        *(uint2*)(w2t + e) = make_uint2(pk2(a, b), pk2(c, dd));
    }
}

// ---------------------------------------------------------------------------
// Split ow into hi/lo bf16.
// ---------------------------------------------------------------------------
__global__ __launch_bounds__(256) void tobf3_kernel(
    const float* __restrict__ ow, unsigned short* __restrict__ owh,
    unsigned short* __restrict__ owl) {
    size_t e = ((size_t)blockIdx.x * 256 + threadIdx.x) * 4;
    float4 v = *(const float4*)(ow + e);
    unsigned short h0 = f2bf(v.x), h1 = f2bf(v.y), h2 = f2bf(v.z), h3 = f2bf(v.w);
    *(uint2*)(owh + e) = make_uint2(pkus(h0, h1), pkus(h2, h3));
    *(uint2*)(owl + e) = make_uint2(
        pk2(v.x - bf2f(h0), v.y - bf2f(h1)), pk2(v.z - bf2f(h2), v.w - bf2f(h3)));
}

// ---------------------------------------------------------------------------
// MFMA bf16 GEMM: 64x64 tile, K=1024. Out per-head [b][n][l][64].
// ---------------------------------------------------------------------------
template <int STOREF, int BFOUT, int KTOUT>
__global__ __launch_bounds__(256) void gemm_bf(const unsigned short* __restrict__ A,
                                               const unsigned short* __restrict__ Bw,
                                               const float* __restrict__ bias,
                                               float* __restrict__ Cf,
                                               unsigned short* __restrict__ Cb,
                                               unsigned short* __restrict__ Ct) {
    __shared__ __align__(16) unsigned short As[64][72];
    __shared__ __align__(16) unsigned short Bs[64][72];
    __shared__ float Os[64][68];
    const int t = threadIdx.x;
    const int r0 = blockIdx.y << 6, c0 = blockIdx.x << 6;
    const int wv = t >> 6, lane = t & 63;
    const int lm = lane & 15, lg = lane >> 4;
    f32x4 acc[4];
#pragma unroll
    for (int i = 0; i < 4; ++i) acc[i] = (f32x4){0.f, 0.f, 0.f, 0.f};
    for (int kc = 0; kc < CD; kc += 64) {
        for (int i = t; i < 512; i += 256) {
            int r = i >> 3, c = (i & 7) * 8;
            *(uint4*)&As[r][c] = *(const uint4*)(A + (size_t)(r0 + r) * CD + kc + c);
            *(uint4*)&Bs[r][c] = *(const uint4*)(Bw + (size_t)(c0 + r) * CD + kc + c);
        }
        __syncthreads();
#pragma unroll
        for (int n16 = 0; n16 < 4; ++n16)
#pragma unroll
            for (int ks = 0; ks < 2; ++ks) {
                short8v a = *(const short8v*)&As[wv * 16 + lm][ks * 32 + lg * 8];
                short8v b = *(const short8v*)&Bs[n16 * 16 + lm][ks * 32 + lg * 8];
                acc[n16] = MFMA16(a, b, acc[n16]);
            }
        __syncthreads();
    }
#pragma unroll
    for (int n16 = 0; n16 < 4; ++n16) {
        float bb = bias[c0 + n16 * 16 + lm];
#pragma unroll
        for (int r = 0; r < 4; ++r)
            Os[wv * 16 + lg * 4 + r][n16 * 16 + lm] = acc[n16][r] + bb;
    }
    __syncthreads();
    const int nh = c0 >> 6;
    const int b = r0 >> 10, lb0 = r0 & 1023;
    for (int i = t; i < 1024; i += 256) {
        int r = i >> 4, c = (i & 15) * 4;
        float4 v = *(const float4*)&Os[r][c];
        size_t base = (((size_t)b * CNH + nh) * CL + lb0 + r) * 64 + c;
        if (STOREF) *(float4*)(Cf + base) = v;
        if (BFOUT) *(uint2*)(Cb + base) = make_uint2(pk2(v.x, v.y), pk2(v.z, v.w));
    }
    if (KTOUT) {
        for (int i = t; i < 512; i += 256) {
            int d = i >> 3, lb = (i & 7) * 8;
            uint4 u;
            u.x = pk2(Os[lb + 0][d], Os[lb + 1][d]);
            u.y = pk2(Os[lb + 2][d], Os[lb + 3][d]);
            u.z = pk2(Os[lb + 4][d], Os[lb + 5][d]);
            u.w = pk2(Os[lb + 6][d], Os[lb + 7][d]);
            *(uint4*)(Ct + (((size_t)b * CNH + nh) * 64 + d) * CL + lb0 + lb) = u;
        }
    }
}

// ---------------------------------------------------------------------------
// Split-precision MFMA o-projection.
// ---------------------------------------------------------------------------
__global__ __launch_bounds__(256) void gemm_obf(const float* __restrict__ A,
                                                const unsigned short* __restrict__ Bh,
                                                const unsigned short* __restrict__ Bl,
                                                const float* __restrict__ bias,
                                                float* __restrict__ C) {
    __shared__ __align__(16) unsigned short SM[4][64][72];
    const int t = threadIdx.x;
    const int r0 = blockIdx.y << 6, c0 = blockIdx.x << 6;
    const int wv = t >> 6, lane = t & 63;
    const int lm = lane & 15, lg = lane >> 4;
    const int b = r0 >> 10, lb0 = r0 & 1023;
    f32x4 acc[4];
#pragma unroll
    for (int i = 0; i < 4; ++i) acc[i] = (f32x4){0.f, 0.f, 0.f, 0.f};
    for (int kc = 0; kc < CD; kc += 64) {
        for (int i = t; i < 1024; i += 256) {
            int r = i >> 4, c4 = (i & 15) * 4;
            int ak = kc + c4, n = ak >> 6, d = ak & 63;
            float4 v = *(const float4*)(A + ((((size_t)b * CNH + n) * CL + lb0 + r) << 6) + d);
            unsigned short h0 = f2bf(v.x), h1 = f2bf(v.y), h2 = f2bf(v.z), h3 = f2bf(v.w);
            *(uint2*)&SM[0][r][c4] = make_uint2(pkus(h0, h1), pkus(h2, h3));
            *(uint2*)&SM[1][r][c4] = make_uint2(
                pk2(v.x - bf2f(h0), v.y - bf2f(h1)), pk2(v.z - bf2f(h2), v.w - bf2f(h3)));
        }
        for (int i = t; i < 512; i += 256) {
            int r = i >> 3, c = (i & 7) * 8;
            *(uint4*)&SM[2][r][c] = *(const uint4*)(Bh + (size_t)(c0 + r) * CD + kc + c);
            *(uint4*)&SM[3][r][c] = *(const uint4*)(Bl + (size_t)(c0 + r) * CD + kc + c);
        }
        __syncthreads();
#pragma unroll
        for (int n16 = 0; n16 < 4; ++n16)
#pragma unroll
            for (int ks = 0; ks < 2; ++ks) {
                short8v ah = *(const short8v*)&SM[0][wv * 16 + lm][ks * 32 + lg * 8];
                short8v al = *(const short8v*)&SM[1][wv * 16 + lm][ks * 32 + lg * 8];
                short8v bh = *(const short8v*)&SM[2][n16 * 16 + lm][ks * 32 + lg * 8];
                short8v bl = *(const short8v*)&SM[3][n16 * 16 + lm][ks * 32 + lg * 8];
                acc[n16] = MFMA16(ah, bh, acc[n16]);
                acc[n16] = MFMA16(ah, bl, acc[n16]);
                acc[n16] = MFMA16(al, bh, acc[n16]);
            }
        __syncthreads();
    }
    float(*Os)[68] = (float(*)[68])SM;
#pragma unroll
    for (int n16 = 0; n16 < 4; ++n16) {
        float bb = bias[c0 + n16 * 16 + lm];
#pragma unroll
        for (int r = 0; r < 4; ++r)
            Os[wv * 16 + lg * 4 + r][n16 * 16 + lm] = acc[n16][r] + bb;
    }
    __syncthreads();
    for (int i = t; i < 1024; i += 256) {
        int r = i >> 4, c = (i & 15) * 4;
        *(float4*)(C + (size_t)(r0 + r) * CD + c0 + c) = *(const float4*)&Os[r][c];
    }
}

// ---------------------------------------------------------------------------
// lr / log_wd projections.
// ---------------------------------------------------------------------------
__global__ __launch_bounds__(64) void lrwd_kernel(
    const float* __restrict__ x, const float* __restrict__ lblr,
    const float* __restrict__ fclr_w, const float* __restrict__ fclr_b,
    const float* __restrict__ lbwd, const float* __restrict__ fcwd_w,
    const float* __restrict__ fcwd_b, float* __restrict__ lrp,
    float* __restrict__ logwd) {
    const int r = blockIdx.x;
    const int b = r >> 10, l = r & 1023;
    const int lane = threadIdx.x;
    float xv[16];
#pragma unroll
    for (int j = 0; j < 16; ++j) xv[j] = x[(size_t)r * CD + lane + 64 * j];
    for (int n = 0; n < CNH; ++n) {
        float d1 = 0.f, d2 = 0.f;
#pragma unroll
        for (int j = 0; j < 16; ++j) {
            d1 += xv[j] * fclr_w[(size_t)n * CD + lane + 64 * j];
            d2 += xv[j] * fcwd_w[(size_t)n * CD + lane + 64 * j];
        }
#pragma unroll
        for (int s = 32; s > 0; s >>= 1) {
            d1 += __shfl_down(d1, s);
            d2 += __shfl_down(d2, s);
        }
        if (lane == 0) {
            lrp[((size_t)b * CNH + n) * CL + l] = __expf(lblr[n]) * sigf(d1 + fclr_b[n]);
            logwd[((size_t)b * CNH + n) * CL + l] =
                log1pf(-__expf(lbwd[n]) * sigf(d2 + fcwd_b[n]));
        }
    }
}

// ---------------------------------------------------------------------------
// Inclusive prefix sum of log_wd -> cum, plus wdc = exp(cum).
// ---------------------------------------------------------------------------
__global__ __launch_bounds__(64) void scan_kernel(float* __restrict__ cum,
                                                  float* __restrict__ wdc) {
    const int bn = blockIdx.x;
    const int lane = threadIdx.x;
    float* p = cum + (size_t)bn * CL;
    float v[16];
#pragma unroll
    for (int j = 0; j < 16; ++j) v[j] = p[lane * 16 + j];
#pragma unroll
    for (int j = 1; j < 16; ++j) v[j] += v[j - 1];
    float tot = v[15];
    float inc = tot;
#pragma unroll
    for (int s = 1; s < 64; s <<= 1) {
        float tv = __shfl_up(inc, s);
        if (lane >= s) inc += tv;
    }
    const float pre = inc - tot;
#pragma unroll
    for (int j = 0; j < 16; ++j) {
        float c = pre + v[j];
        p[lane * 16 + j] = c;
        wdc[(size_t)bn * CL + lane * 16 + j] = __expf(c);
    }
}

// ---------------------------------------------------------------------------
// MFMA MLP fwd/bwd over 64 tokens.
// ---------------------------------------------------------------------------
__global__ __launch_bounds__(256) void mlp_mfma(
    const unsigned short* __restrict__ kbf, const float* __restrict__ vh,
    const unsigned short* __restrict__ w1bf, const unsigned short* __restrict__ w2bf,
    const unsigned short* __restrict__ w2tbf, unsigned short* __restrict__ x2bf,
    unsigned short* __restrict__ x2t, unsigned short* __restrict__ gz1t,
    unsigned short* __restrict__ gz2t) {
    __shared__ __align__(16) unsigned short RA[128][72];
    __shared__ __align__(16) unsigned short RB[64][72];
    __shared__ __align__(16) unsigned short RC[64][136];
    __shared__ __align__(16) unsigned short X2s[64][136];
    const int bn = blockIdx.y, l0 = blockIdx.x << 6;
    const int t = threadIdx.x;
    const int wv = t >> 6, lane = t & 63;
    const int lm = lane & 15, lg = lane >> 4;
    {
        const unsigned short* kg = kbf + ((size_t)bn * CL + l0) * CHD;
        for (int i = t; i < 512; i += 256) {
            int r = i >> 3, c = (i & 7) * 8;
            *(uint4*)&RB[r][c] = *(const uint4*)(kg + (size_t)r * CHD + c);
        }
        const unsigned short* w1g = w1bf + (size_t)bn * CHDH * CHD;
        for (int i = t; i < 1024; i += 256) {
            int r = i >> 3, c = (i & 7) * 8;
            *(uint4*)&RA[r][c] = *(const uint4*)(w1g + (size_t)r * CHD + c);
        }
        const unsigned short* w2g = w2bf + (size_t)bn * CHD * CHDH;
        for (int i = t; i < 1024; i += 256) {
            int r = i >> 4, c = (i & 15) * 8;
            *(uint4*)&RC[r][c] = *(const uint4*)(w2g + (size_t)r * CHDH + c);
        }
    }
    __syncthreads();
    f32x4 acc1[4][2];
#pragma unroll
    for (int i = 0; i < 4; ++i)
#pragma unroll
        for (int j = 0; j < 2; ++j) acc1[i][j] = (f32x4){0.f, 0.f, 0.f, 0.f};
#pragma unroll
    for (int m16 = 0; m16 < 4; ++m16)
#pragma unroll
        for (int hh = 0; hh < 2; ++hh) {
            int h16 = wv * 2 + hh;
#pragma unroll
            for (int ks = 0; ks < 2; ++ks) {
                short8v a = *(const short8v*)&RB[m16 * 16 + lm][ks * 32 + lg * 8];
                short8v b = *(const short8v*)&RA[h16 * 16 + lm][ks * 32 + lg * 8];
                acc1[m16][hh] = MFMA16(a, b, acc1[m16][hh]);
            }
        }
#pragma unroll
    for (int m16 = 0; m16 < 4; ++m16)
#pragma unroll
        for (int hh = 0; hh < 2; ++hh)
#pragma unroll
            for (int r = 0; r < 4; ++r) {
                float a = acc1[m16][hh][r];
                X2s[m16 * 16 + lg * 4 + r][(wv * 2 + hh) * 16 + lm] = f2bf(a * sigf(a));
            }
    __syncthreads();
    {
        const unsigned short* w2tg = w2tbf + (size_t)bn * CHDH * CHD;
        for (int i = t; i < 1024; i += 256) {
            int r = i >> 3, c = (i & 7) * 8;
            *(uint4*)&RA[r][c] = *(const uint4*)(w2tg + (size_t)r * CHD + c);
        }
    }
    {
        f32x4 acc2[4];
#pragma unroll
        for (int i = 0; i < 4; ++i) acc2[i] = (f32x4){0.f, 0.f, 0.f, 0.f};
#pragma unroll
        for (int m16 = 0; m16 < 4; ++m16)
#pragma unroll
            for (int ks = 0; ks < 4; ++ks) {
                short8v a = *(const short8v*)&X2s[m16 * 16 + lm][ks * 32 + lg * 8];
                short8v b = *(const short8v*)&RC[wv * 16 + lm][ks * 32 + lg * 8];
                acc2[m16] = MFMA16(a, b, acc2[m16]);
            }
#pragma unroll
        for (int m16 = 0; m16 < 4; ++m16)
#pragma unroll
            for (int r = 0; r < 4; ++r) {
                int l = l0 + m16 * 16 + lg * 4 + r;
                float v = vh[((size_t)bn * CL + l) * 64 + wv * 16 + lm];
                RB[m16 * 16 + lg * 4 + r][wv * 16 + lm] = f2bf(acc2[m16][r] - v);
            }
    }
    __syncthreads();
#pragma unroll
    for (int m16 = 0; m16 < 4; ++m16)
#pragma unroll
        for (int hh = 0; hh < 2; ++hh) {
            int h16 = wv * 2 + hh;
            f32x4 p = (f32x4){0.f, 0.f, 0.f, 0.f};
#pragma unroll
            for (int ks = 0; ks < 2; ++ks) {
                short8v a = *(const short8v*)&RB[m16 * 16 + lm][ks * 32 + lg * 8];
                short8v b = *(const short8v*)&RA[h16 * 16 + lm][ks * 32 + lg * 8];
                p = MFMA16(a, b, p);
            }
#pragma unroll
            for (int r = 0; r < 4; ++r) {
                float zz = acc1[m16][hh][r];
                float s = sigf(zz);
                float sil = zz * s;
                RC[m16 * 16 + lg * 4 + r][h16 * 16 + lm] =
                    f2bf((sil + s * (1.f - sil)) * p[r]);
            }
        }
    __syncthreads();
    for (int i = t; i < 1024; i += 256) {
        int r = i >> 4, c = (i & 15) * 8;
        *(uint4*)(x2bf + ((size_t)bn * CL + l0 + r) * CHDH + c) = *(const uint4*)&X2s[r][c];
    }
    for (int i = t; i < 1024; i += 256) {
        int h = i >> 3, lb = (i & 7) * 8;
        uint4 u;
        u.x = pkus(X2s[lb + 0][h], X2s[lb + 1][h]);
        u.y = pkus(X2s[lb + 2][h], X2s[lb + 3][h]);
        u.z = pkus(X2s[lb + 4][h], X2s[lb + 5][h]);
        u.w = pkus(X2s[lb + 6][h], X2s[lb + 7][h]);
        *(uint4*)(x2t + ((size_t)bn * CHDH + h) * CL + l0 + lb) = u;
    }
    for (int i = t; i < 1024; i += 256) {
        int h = i >> 3, lb = (i & 7) * 8;
        uint4 u;
        u.x = pkus(RC[lb + 0][h], RC[lb + 1][h]);
        u.y = pkus(RC[lb + 2][h], RC[lb + 3][h]);
        u.z = pkus(RC[lb + 4][h], RC[lb + 5][h]);
        u.w = pkus(RC[lb + 6][h], RC[lb + 7][h]);
        *(uint4*)(gz1t + ((size_t)bn * CHDH + h) * CL + l0 + lb) = u;
    }
    for (int i = t; i < 512; i += 256) {
        int d = i >> 3, lb = (i & 7) * 8;
        uint4 u;
        u.x = pkus(RB[lb + 0][d], RB[lb + 1][d]);
        u.y = pkus(RB[lb + 2][d], RB[lb + 3][d]);
        u.z = pkus(RB[lb + 4][d], RB[lb + 5][d]);
        u.w = pkus(RB[lb + 6][d], RB[lb + 7][d]);
        *(uint4*)(gz2t + ((size_t)bn * CHD + d) * CL + l0 + lb) = u;
    }
}

// ---------------------------------------------------------------------------
// attn1 (paired m-tiles, XCD-swizzled, software-pipelined: 1 barrier/iter).
// Buffers: Kb2[2], GT3[3] (W1 init in GT3[2]), Pm2[2], lr/cum[2].
// ---------------------------------------------------------------------------
__global__ __launch_bounds__(512) void attn1_mfma(
    const unsigned short* __restrict__ qbf, const unsigned short* __restrict__ kbf,
    const unsigned short* __restrict__ gz1t, const unsigned short* __restrict__ w1bf,
    const float* __restrict__ lrp, const float* __restrict__ cump,
    const float* __restrict__ wdcp, unsigned short* __restrict__ x2q) {
    __shared__ __align__(16) unsigned short Qb[128][72];
    __shared__ __align__(16) unsigned short Kb2[2][64][72];
    __shared__ __align__(16) unsigned short GT3[3][128][72];
    __shared__ __align__(16) unsigned short Pm2[2][128][72];
    __shared__ float lrl2[2][64], cuml2[2][64], cumm[128], wdcm[128];
    const int bx = blockIdx.x, by = blockIdx.y;
    const int bn = (bx << 2) + (by >> 3);  // XCD swizzle
    const int p = by & 7;
    const int mtB = 15 - p;
    const int NT = mtB + 1;  // >= 9
    const int m0A = p << 6, m0B = mtB << 6;
    const int t = threadIdx.x;
    const int wv = t >> 6, lane = t & 63;
    const int grp = wv >> 2, w4 = wv & 3;
    const int lm = lane & 15, lg = lane >> 4;
    const int qbase = grp << 6;
    const int m0 = grp ? m0B : m0A;
    const int mtsel = grp ? mtB : p;
    const int sr = t >> 3, sc = (t & 7) * 8;
    uint4 pkv, pgv[2];
    float plr, pcu;
    // issue tile-0 loads
    {
        const unsigned short* kg = kbf + (size_t)bn * CL * CHD;
        pkv = *(const uint4*)(kg + (size_t)sr * CHD + sc);
        const unsigned short* gg = gz1t + (size_t)bn * CHDH * CL;
        pgv[0] = *(const uint4*)(gg + (size_t)sr * CL + sc);
        pgv[1] = *(const uint4*)(gg + (size_t)(sr + 64) * CL + sc);
        if (t < 64) {
            plr = lrp[(size_t)bn * CL + t];
            pcu = cump[(size_t)bn * CL + t];
        }
    }
    // stage Q (both tiles) + W1 into GT3[2]
    {
        const unsigned short* qgA = qbf + ((size_t)bn * CL + m0A) * CHD;
        const unsigned short* qgB = qbf + ((size_t)bn * CL + m0B) * CHD;
        *(uint4*)&Qb[sr][sc] = *(const uint4*)(qgA + (size_t)sr * CHD + sc);
        *(uint4*)&Qb[64 + sr][sc] = *(const uint4*)(qgB + (size_t)sr * CHD + sc);
        const unsigned short* wg = w1bf + (size_t)bn * CHDH * CHD;
        *(uint4*)&GT3[2][sr][sc] = *(const uint4*)(wg + (size_t)sr * CHD + sc);
        *(uint4*)&GT3[2][64 + sr][sc] = *(const uint4*)(wg + (size_t)(sr + 64) * CHD + sc);
        if (t < 128) {
            int mm = (t < 64) ? (m0A + t) : (m0B + t - 64);
            cumm[t] = cump[(size_t)bn * CL + mm];
            wdcm[t] = wdcp[(size_t)bn * CL + mm];
        }
    }
    __syncthreads();
    // R1: qf cache + init MFMA (GT3[2]) + publish(0) + loads(1)
    short8v qf[4][2];
#pragma unroll
    for (int m16 = 0; m16 < 4; ++m16)
#pragma unroll
        for (int ks = 0; ks < 2; ++ks)
            qf[m16][ks] = *(const short8v*)&Qb[qbase + m16 * 16 + lm][ks * 32 + lg * 8];
    f32x4 acc[4][2];
#pragma unroll
    for (int i = 0; i < 4; ++i)
#pragma unroll
        for (int j = 0; j < 2; ++j) acc[i][j] = (f32x4){0.f, 0.f, 0.f, 0.f};
    {
        short8v wf[2][2];
#pragma unroll
        for (int hh = 0; hh < 2; ++hh)
#pragma unroll
            for (int ks = 0; ks < 2; ++ks)
                wf[hh][ks] =
                    *(const short8v*)&GT3[2][(w4 * 2 + hh) * 16 + lm][ks * 32 + lg * 8];
#pragma unroll
        for (int m16 = 0; m16 < 4; ++m16)
#pragma unroll
            for (int hh = 0; hh < 2; ++hh)
#pragma unroll
                for (int ks = 0; ks < 2; ++ks)
                    acc[m16][hh] = MFMA16(qf[m16][ks], wf[hh][ks], acc[m16][hh]);
    }
#pragma unroll
    for (int m16 = 0; m16 < 4; ++m16) {
#pragma unroll
        for (int r = 0; r < 4; ++r) {
            float w = wdcm[qbase + m16 * 16 + lg * 4 + r];
            acc[m16][0][r] *= w;
            acc[m16][1][r] *= w;
        }
    }
    // publish(0)
    *(uint4*)&Kb2[0][sr][sc] = pkv;
    *(uint4*)&GT3[0][sr][sc] = pgv[0];
    *(uint4*)&GT3[0][64 + sr][sc] = pgv[1];
    if (t < 64) { lrl2[0][t] = plr; cuml2[0][t] = pcu; }
    // loads(1)
    {
        const unsigned short* kg = kbf + ((size_t)bn * CL + 64) * CHD;
        pkv = *(const uint4*)(kg + (size_t)sr * CHD + sc);
        const unsigned short* gg = gz1t + (size_t)bn * CHDH * CL + 64;
        pgv[0] = *(const uint4*)(gg + (size_t)sr * CL + sc);
        pgv[1] = *(const uint4*)(gg + (size_t)(sr + 64) * CL + sc);
        if (t < 64) {
            plr = lrp[(size_t)bn * CL + 64 + t];
            pcu = cump[(size_t)bn * CL + 64 + t];
        }
    }
    __syncthreads();
    // R2: scores(0) + publish(1) + loads(2)
    {
        short8v kf[2];
#pragma unroll
        for (int ks = 0; ks < 2; ++ks)
            kf[ks] = *(const short8v*)&Kb2[0][w4 * 16 + lm][ks * 32 + lg * 8];
#pragma unroll
        for (int m16 = 0; m16 < 4; ++m16) {
            f32x4 s = (f32x4){0.f, 0.f, 0.f, 0.f};
#pragma unroll
            for (int ks = 0; ks < 2; ++ks) s = MFMA16(kf[ks], qf[m16][ks], s);
            int mloc = m16 * 16 + lm;
            int mabs = m0 + mloc;
            float cm = cumm[qbase + mloc];
            unsigned short pv[4];
#pragma unroll
            for (int r = 0; r < 4; ++r) {
                int lloc = w4 * 16 + lg * 4 + r;
                float val = (mabs >= lloc)
                                ? s[r] * lrl2[0][lloc] * __expf(cm - cuml2[0][lloc])
                                : 0.f;
                pv[r] = f2bf(val);
            }
            *(uint2*)&Pm2[0][qbase + mloc][w4 * 16 + lg * 4] =
                make_uint2(pkus(pv[0], pv[1]), pkus(pv[2], pv[3]));
        }
    }
    // publish(1)
    *(uint4*)&Kb2[1][sr][sc] = pkv;
    *(uint4*)&GT3[1][sr][sc] = pgv[0];
    *(uint4*)&GT3[1][64 + sr][sc] = pgv[1];
    if (t < 64) { lrl2[1][t] = plr; cuml2[1][t] = pcu; }
    // loads(2)
    if (2 < NT) {
        const unsigned short* kg = kbf + ((size_t)bn * CL + 128) * CHD;
        pkv = *(const uint4*)(kg + (size_t)sr * CHD + sc);
        const unsigned short* gg = gz1t + (size_t)bn * CHDH * CL + 128;
        pgv[0] = *(const uint4*)(gg + (size_t)sr * CL + sc);
        pgv[1] = *(const uint4*)(gg + (size_t)(sr + 64) * CL + sc);
        if (t < 64) {
            plr = lrp[(size_t)bn * CL + 128 + t];
            pcu = cump[(size_t)bn * CL + 128 + t];
        }
    }
    __syncthreads();
    // main loop: apply(i-1) + scores(i) + publish(i+1) + loads(i+2), 1 barrier
    for (int i = 1; i < NT; ++i) {
        const int pb = (i - 1) & 1, pg3 = (i - 1) % 3;
        if (i - 1 <= mtsel) {
            short8v gt[2][2], pm[4][2];
#pragma unroll
            for (int hh = 0; hh < 2; ++hh)
#pragma unroll
                for (int ks = 0; ks < 2; ++ks)
                    gt[hh][ks] = *(const short8v*)&GT3[pg3][(w4 * 2 + hh) * 16 + lm]
                                                      [ks * 32 + lg * 8];
#pragma unroll
            for (int m16 = 0; m16 < 4; ++m16)
#pragma unroll
                for (int ks = 0; ks < 2; ++ks)
                    pm[m16][ks] = *(const short8v*)&Pm2[pb][qbase + m16 * 16 + lm]
                                                       [ks * 32 + lg * 8];
#pragma unroll
            for (int m16 = 0; m16 < 4; ++m16)
#pragma unroll
                for (int hh = 0; hh < 2; ++hh) {
                    f32x4 pf = (f32x4){0.f, 0.f, 0.f, 0.f};
#pragma unroll
                    for (int ks = 0; ks < 2; ++ks)
                        pf = MFMA16(pm[m16][ks], gt[hh][ks], pf);
#pragma unroll
                    for (int r = 0; r < 4; ++r) acc[m16][hh][r] -= pf[r];
                }
        }
        const int cb = i & 1;
        const int l0 = i << 6;
        if (i <= mtsel) {
            short8v kf[2];
#pragma unroll
            for (int ks = 0; ks < 2; ++ks)
                kf[ks] = *(const short8v*)&Kb2[cb][w4 * 16 + lm][ks * 32 + lg * 8];
#pragma unroll
            for (int m16 = 0; m16 < 4; ++m16) {
                f32x4 s = (f32x4){0.f, 0.f, 0.f, 0.f};
#pragma unroll
                for (int ks = 0; ks < 2; ++ks) s = MFMA16(kf[ks], qf[m16][ks], s);
                int mloc = m16 * 16 + lm;
                int mabs = m0 + mloc;
                float cm = cumm[qbase + mloc];
                unsigned short pv[4];
#pragma unroll
                for (int r = 0; r < 4; ++r) {
                    int lloc = w4 * 16 + lg * 4 + r;
                    float val = (mabs >= l0 + lloc)
                                    ? s[r] * lrl2[cb][lloc] * __expf(cm - cuml2[cb][lloc])
                                    : 0.f;
                    pv[r] = f2bf(val);
                }
                *(uint2*)&Pm2[cb][qbase + mloc][w4 * 16 + lg * 4] =
                    make_uint2(pkus(pv[0], pv[1]), pkus(pv[2], pv[3]));
            }
        }
        if (i + 1 < NT) {
            const int nb = (i + 1) & 1, ng3 = (i + 1) % 3;
            *(uint4*)&Kb2[nb][sr][sc] = pkv;
            *(uint4*)&GT3[ng3][sr][sc] = pgv[0];
            *(uint4*)&GT3[ng3][64 + sr][sc] = pgv[1];
            if (t < 64) { lrl2[nb][t] = plr; cuml2[nb][t] = pcu; }
        }
        if (i + 2 < NT) {
            const int ln = (i + 2) << 6;
            const unsigned short* kg = kbf + ((size_t)bn * CL + ln) * CHD;
            pkv = *(const uint4*)(kg + (size_t)sr * CHD + sc);
            const unsigned short* gg = gz1t + (size_t)bn * CHDH * CL + ln;
            pgv[0] = *(const uint4*)(gg + (size_t)sr * CL + sc);
            pgv[1] = *(const uint4*)(gg + (size_t)(sr + 64) * CL + sc);
            if (t < 64) {
                plr = lrp[(size_t)bn * CL + ln + t];
                pcu = cump[(size_t)bn * CL + ln + t];
            }
        }
        __syncthreads();
    }
    // final apply(NT-1)
    if (NT - 1 <= mtsel) {
        const int pb = (NT - 1) & 1, pg3 = (NT - 1) % 3;
        short8v gt[2][2], pm[4][2];
#pragma unroll
        for (int hh = 0; hh < 2; ++hh)
#pragma unroll
            for (int ks = 0; ks < 2; ++ks)
                gt[hh][ks] = *(const short8v*)&GT3[pg3][(w4 * 2 + hh) * 16 + lm]
                                                  [ks * 32 + lg * 8];
#pragma unroll
        for (int m16 = 0; m16 < 4; ++m16)
#pragma unroll
            for (int ks = 0; ks < 2; ++ks)
                pm[m16][ks] = *(const short8v*)&Pm2[pb][qbase + m16 * 16 + lm]
                                                   [ks * 32 + lg * 8];
#pragma unroll
        for (int m16 = 0; m16 < 4; ++m16)
#pragma unroll
            for (int hh = 0; hh < 2; ++hh) {
                f32x4 pf = (f32x4){0.f, 0.f, 0.f, 0.f};
#pragma unroll
                for (int ks = 0; ks < 2; ++ks) pf = MFMA16(pm[m16][ks], gt[hh][ks], pf);
#pragma unroll
                for (int r = 0; r < 4; ++r) acc[m16][hh][r] -= pf[r];
            }
    }
    __syncthreads();
    {
        unsigned short(*Ob)[136] = (unsigned short(*)[136])Pm2;
#pragma unroll
        for (int m16 = 0; m16 < 4; ++m16)
#pragma unroll
            for (int hh = 0; hh < 2; ++hh) {
                int h = (w4 * 2 + hh) * 16 + lm;
#pragma unroll
                for (int r = 0; r < 4; ++r) {
                    int mloc = m16 * 16 + lg * 4 + r;
                    float a = acc[m16][hh][r];
                    Ob[qbase + mloc][h] = f2bf(a * sigf(a));
                }
            }
        __syncthreads();
        unsigned short* og = x2q + (size_t)bn * CL * CHDH;
        for (int i = t; i < 2048; i += 512) {
            int r = i >> 4, c = (i & 15) * 8;
            int gm = (r < 64) ? (m0A + r) : (m0B + r - 64);
            *(uint4*)(og + (size_t)gm * CHDH + c) = *(const uint4*)&Ob[r][c];
        }
    }
}

// ---------------------------------------------------------------------------
// attn2 (paired m-tiles, XCD-swizzled, software-pipelined: 1 barrier/iter).
// Buffers: X2l2[2] (W2 init in X2l2[1]), GT3[3], Pm2[2].
// ---------------------------------------------------------------------------
__global__ __launch_bounds__(512) void attn2_mfma(
    const unsigned short* __restrict__ x2q, const unsigned short* __restrict__ x2bf,
    const unsigned short* __restrict__ gz2t, const unsigned short* __restrict__ w2bf,
    const float* __restrict__ lrp, const float* __restrict__ cump,
    const float* __restrict__ wdcp, float* __restrict__ z2s) {
    __shared__ __align__(16) unsigned short X2qb[128][136];
    __shared__ __align__(16) unsigned short X2l2[2][64][136];
    __shared__ __align__(16) unsigned short GT3[3][64][72];
    __shared__ __align__(16) unsigned short Pm2[2][128][72];
    __shared__ float lrl2[2][64], cuml2[2][64], cumm[128], wdcm[128];
    const int bx = blockIdx.x, by = blockIdx.y;
    const int bn = (bx << 2) + (by >> 3);  // XCD swizzle
    const int p = by & 7;
    const int mtB = 15 - p;
    const int NT = mtB + 1;
    const int m0A = p << 6, m0B = mtB << 6;
    const int t = threadIdx.x;
    const int wv = t >> 6, lane = t & 63;
    const int grp = wv >> 2, w4 = wv & 3;
    const int lm = lane & 15, lg = lane >> 4;
    const int qbase = grp << 6;
    const int m0 = grp ? m0B : m0A;
    const int mtsel = grp ? mtB : p;
    const int xr = t >> 4, xc = (t & 15) * 8;
    const int gr = t >> 3, gc = (t & 7) * 8;
    uint4 px[2], pgv;
    float plr, pcu;
    // tile-0 loads
    {
        const unsigned short* kg = x2bf + (size_t)bn * CL * CHDH;
        px[0] = *(const uint4*)(kg + (size_t)xr * CHDH + xc);
        px[1] = *(const uint4*)(kg + (size_t)(xr + 32) * CHDH + xc);
        const unsigned short* gg = gz2t + (size_t)bn * CHD * CL;
        pgv = *(const uint4*)(gg + (size_t)gr * CL + gc);
        if (t < 64) {
            plr = lrp[(size_t)bn * CL + t];
            pcu = cump[(size_t)bn * CL + t];
        }
    }
    // stage x2q (both tiles) + W2 into X2l2[1]
    {
        const unsigned short* qgA = x2q + ((size_t)bn * CL + m0A) * CHDH;
        const unsigned short* qgB = x2q + ((size_t)bn * CL + m0B) * CHDH;
        *(uint4*)&X2qb[xr][xc] = *(const uint4*)(qgA + (size_t)xr * CHDH + xc);
        *(uint4*)&X2qb[xr + 32][xc] = *(const uint4*)(qgA + (size_t)(xr + 32) * CHDH + xc);
        *(uint4*)&X2qb[xr + 64][xc] = *(const uint4*)(qgB + (size_t)xr * CHDH + xc);
        *(uint4*)&X2qb[xr + 96][xc] = *(const uint4*)(qgB + (size_t)(xr + 32) * CHDH + xc);
        const unsigned short* wg = w2bf + (size_t)bn * CHD * CHDH;
        *(uint4*)&X2l2[1][xr][xc] = *(const uint4*)(wg + (size_t)xr * CHDH + xc);
        *(uint4*)&X2l2[1][xr + 32][xc] = *(const uint4*)(wg + (size_t)(xr + 32) * CHDH + xc);
        if (t < 128) {
            int mm = (t < 64) ? (m0A + t) : (m0B + t - 64);
            cumm[t] = cump[(size_t)bn * CL + mm];
            wdcm[t] = wdcp[(size_t)bn * CL + mm];
        }
    }
    __syncthreads();
    // R1: qf cache + init (W2 in X2l2[1]) + publish(0) + loads(1)
    short8v qf[4][4];
#pragma unroll
    for (int m16 = 0; m16 < 4; ++m16)
#pragma unroll
        for (int ks = 0; ks < 4; ++ks)
            qf[m16][ks] =
                *(const short8v*)&X2qb[qbase + m16 * 16 + lm][ks * 32 + lg * 8];
    f32x4 acc[4];
#pragma unroll
    for (int i = 0; i < 4; ++i) acc[i] = (f32x4){0.f, 0.f, 0.f, 0.f};
    {
        short8v wf[4];
#pragma unroll
        for (int ks = 0; ks < 4; ++ks)
            wf[ks] = *(const short8v*)&X2l2[1][w4 * 16 + lm][ks * 32 + lg * 8];
#pragma unroll
        for (int m16 = 0; m16 < 4; ++m16)
#pragma unroll
            for (int ks = 0; ks < 4; ++ks)
                acc[m16] = MFMA16(qf[m16][ks], wf[ks], acc[m16]);
    }
#pragma unroll
    for (int m16 = 0; m16 < 4; ++m16)
#pragma unroll
        for (int r = 0; r < 4; ++r) acc[m16][r] *= wdcm[qbase + m16 * 16 + lg * 4 + r];
    // publish(0)
    *(uint4*)&X2l2[0][xr][xc] = px[0];
    *(uint4*)&X2l2[0][xr + 32][xc] = px[1];
    *(uint4*)&GT3[0][gr][gc] = pgv;
    if (t < 64) { lrl2[0][t] = plr; cuml2[0][t] = pcu; }
    // loads(1)
    {
        const unsigned short* kg = x2bf + ((size_t)bn * CL + 64) * CHDH;
        px[0] = *(const uint4*)(kg + (size_t)xr * CHDH + xc);
        px[1] = *(const uint4*)(kg + (size_t)(xr + 32) * CHDH + xc);
        const unsigned short* gg = gz2t + (size_t)bn * CHD * CL + 64;
        pgv = *(const uint4*)(gg + (size_t)gr * CL + gc);
        if (t < 64) {
            plr = lrp[(size_t)bn * CL + 64 + t];
            pcu = cump[(size_t)bn * CL + 64 + t];
        }
    }
    __syncthreads();
    // R2: scores(0) + publish(1) + loads(2)
    {
        short8v kf[4];
#pragma unroll
        for (int ks = 0; ks < 4; ++ks)
            kf[ks] = *(const short8v*)&X2l2[0][w4 * 16 + lm][ks * 32 + lg * 8];
#pragma unroll
        for (int m16 = 0; m16 < 4; ++m16) {
            f32x4 s = (f32x4){0.f, 0.f, 0.f, 0.f};
#pragma unroll
            for (int ks = 0; ks < 4; ++ks) s = MFMA16(kf[ks], qf[m16][ks], s);
            int mloc = m16 * 16 + lm;
            int mabs = m0 + mloc;
            float cm = cumm[qbase + mloc];
            unsigned short pv[4];
#pragma unroll
            for (int r = 0; r < 4; ++r) {
                int lloc = w4 * 16 + lg * 4 + r;
                float val = (mabs >= lloc)
                                ? s[r] * lrl2[0][lloc] * __expf(cm - cuml2[0][lloc])
                                : 0.f;
                pv[r] = f2bf(val);
            }
            *(uint2*)&Pm2[0][qbase + mloc][w4 * 16 + lg * 4] =
                make_uint2(pkus(pv[0], pv[1]), pkus(pv[2], pv[3]));
        }
    }
    // publish(1)
    *(uint4*)&X2l2[1][xr][xc] = px[0];
    *(uint4*)&X2l2[1][xr + 32][xc] = px[1];
    *(uint4*)&GT3[1][gr][gc] = pgv;
    if (t < 64) { lrl2[1][t] = plr; cuml2[1][t] = pcu; }
    // loads(2)
    if (2 < NT) {
        const unsigned short* kg = x2bf + ((size_t)bn * CL + 128) * CHDH;
        px[0] = *(const uint4*)(kg + (size_t)xr * CHDH + xc);
        px[1] = *(const uint4*)(kg + (size_t)(xr + 32) * CHDH + xc);
        const unsigned short* gg = gz2t + (size_t)bn * CHD * CL + 128;
        pgv = *(const uint4*)(gg + (size_t)gr * CL + gc);
        if (t < 64) {
            plr = lrp[(size_t)bn * CL + 128 + t];
            pcu = cump[(size_t)bn * CL + 128 + t];
        }
    }
    __syncthreads();
    for (int i = 1; i < NT; ++i) {
        const int pb = (i - 1) & 1, pg3 = (i - 1) % 3;
        if (i - 1 <= mtsel) {
            short8v gt[2], pm[4][2];
#pragma unroll
            for (int ks = 0; ks < 2; ++ks)
                gt[ks] = *(const short8v*)&GT3[pg3][w4 * 16 + lm][ks * 32 + lg * 8];
#pragma unroll
            for (int m16 = 0; m16 < 4; ++m16)
#pragma unroll
                for (int ks = 0; ks < 2; ++ks)
                    pm[m16][ks] = *(const short8v*)&Pm2[pb][qbase + m16 * 16 + lm]
                                                       [ks * 32 + lg * 8];
#pragma unroll
            for (int m16 = 0; m16 < 4; ++m16) {
                f32x4 pf = (f32x4){0.f, 0.f, 0.f, 0.f};
#pragma unroll
                for (int ks = 0; ks < 2; ++ks) pf = MFMA16(pm[m16][ks], gt[ks], pf);
#pragma unroll
                for (int r = 0; r < 4; ++r) acc[m16][r] -= pf[r];
            }
        }
        const int cb = i & 1;
        const int l0 = i << 6;
        if (i <= mtsel) {
            short8v kf[4];
#pragma unroll
            for (int ks = 0; ks < 4; ++ks)
                kf[ks] = *(const short8v*)&X2l2[cb][w4 * 16 + lm][ks * 32 + lg * 8];
#pragma unroll
            for (int m16 = 0; m16 < 4; ++m16) {
                f32x4 s = (f32x4){0.f, 0.f, 0.f, 0.f};
#pragma unroll
                for (int ks = 0; ks < 4; ++ks) s = MFMA16(kf[ks], qf[m16][ks], s);
                int mloc = m16 * 16 + lm;
                int mabs = m0 + mloc;
                float cm = cumm[qbase + mloc];
                unsigned short pv[4];
#pragma unroll
                for (int r = 0; r < 4; ++r) {
                    int lloc = w4 * 16 + lg * 4 + r;
                    float val = (mabs >= l0 + lloc)
                                    ? s[r] * lrl2[cb][lloc] * __expf(cm - cuml2[cb][lloc])
                                    : 0.f;
                    pv[r] = f2bf(val);
                }
                *(uint2*)&Pm2[cb][qbase + mloc][w4 * 16 + lg * 4] =
                    make_uint2(pkus(pv[0], pv[1]), pkus(pv[2], pv[3]));
            }
        }
        if (i + 1 < NT) {
            const int nb = (i + 1) & 1, ng3 = (i + 1) % 3;
            *(uint4*)&X2l2[nb][xr][xc] = px[0];
            *(uint4*)&X2l2[nb][xr + 32][xc] = px[1];
            *(uint4*)&GT3[ng3][gr][gc] = pgv;
            if (t < 64) { lrl2[nb][t] = plr; cuml2[nb][t] = pcu; }
        }
        if (i + 2 < NT) {
            const int ln = (i + 2) << 6;
            const unsigned short* kg = x2bf + ((size_t)bn * CL + ln) * CHDH;
            px[0] = *(const uint4*)(kg + (size_t)xr * CHDH + xc);
            px[1] = *(const uint4*)(kg + (size_t)(xr + 32) * CHDH + xc);
            const unsigned short* gg = gz2t + (size_t)bn * CHD * CL + ln;
            pgv = *(const uint4*)(gg + (size_t)gr * CL + gc);
            if (t < 64) {
                plr = lrp[(size_t)bn * CL + ln + t];
                pcu = cump[(size_t)bn * CL + ln + t];
            }
        }
        __syncthreads();
    }
    if (NT - 1 <= mtsel) {
        const int pb = (NT - 1) & 1, pg3 = (NT - 1) % 3;
        short8v gt[2], pm[4][2];
#pragma unroll
        for (int ks = 0; ks < 2; ++ks)
            gt[ks] = *(const short8v*)&GT3[pg3][w4 * 16 + lm][ks * 32 + lg * 8];
#pragma unroll
        for (int m16 = 0; m16 < 4; ++m16)
#pragma unroll
            for (int ks = 0; ks < 2; ++ks)
                pm[m16][ks] = *(const short8v*)&Pm2[pb][qbase + m16 * 16 + lm]
                                                   [ks * 32 + lg * 8];
#pragma unroll
        for (int m16 = 0; m16 < 4; ++m16) {
            f32x4 pf = (f32x4){0.f, 0.f, 0.f, 0.f};
#pragma unroll
            for (int ks = 0; ks < 2; ++ks) pf = MFMA16(pm[m16][ks], gt[ks], pf);
#pragma unroll
            for (int r = 0; r < 4; ++r) acc[m16][r] -= pf[r];
        }
    }
    __syncthreads();
    {
        float(*Os)[68] = (float(*)[68])X2qb;
#pragma unroll
        for (int m16 = 0; m16 < 4; ++m16)
#pragma unroll
            for (int r = 0; r < 4; ++r)
                Os[qbase + m16 * 16 + lg * 4 + r][w4 * 16 + lm] = acc[m16][r];
        __syncthreads();
        float* zg = z2s + (size_t)bn * CL * CHD;
        for (int i = t; i < 2048; i += 512) {
            int r = i >> 4, c = (i & 15) << 2;
            int gm = (r < 64) ? (m0A + r) : (m0B + r - 64);
            *(float4*)(zg + (size_t)gm * CHD + c) = *(const float4*)&Os[r][c];
        }
    }
}

// ---------------------------------------------------------------------------
// W1_next partial (split-K over l).
// ---------------------------------------------------------------------------
__global__ __launch_bounds__(256) void w1n_part(
    const unsigned short* __restrict__ gz1t, const unsigned short* __restrict__ ktbf,
    const float* __restrict__ lrp, const float* __restrict__ cump,
    float* __restrict__ part) {
    __shared__ __align__(16) unsigned short Ab[128][72];
    __shared__ __align__(16) unsigned short Bb[64][72];
    __shared__ float coefA[128];
    const int ks = blockIdx.x, bn = blockIdx.y, t = threadIdx.x;
    const int lc0 = ks << 7;
    const int wv = t >> 6, lane = t & 63;
    const int lm = lane & 15, lg = lane >> 4;
    const float cum_last = cump[(size_t)bn * CL + CL - 1];
    if (t < 128)
        coefA[t] = lrp[(size_t)bn * CL + lc0 + t] *
                   __expf(cum_last - cump[(size_t)bn * CL + lc0 + t]);
    f32x4 acc[2][4];
#pragma unroll
    for (int i = 0; i < 2; ++i)
#pragma unroll
        for (int j = 0; j < 4; ++j) acc[i][j] = (f32x4){0.f, 0.f, 0.f, 0.f};
    for (int lo = 0; lo < 128; lo += 64) {
        __syncthreads();
        for (int i = t; i < 1024; i += 256) {
            int h = i >> 3, cc = (i & 7) * 8;
            uint4 g = *(const uint4*)(gz1t + ((size_t)bn * CHDH + h) * CL + lc0 + lo + cc);
            unsigned short* gp = (unsigned short*)&g;
            uint4 o;
            o.x = pk2(bf2f(gp[0]) * coefA[lo + cc + 0], bf2f(gp[1]) * coefA[lo + cc + 1]);
            o.y = pk2(bf2f(gp[2]) * coefA[lo + cc + 2], bf2f(gp[3]) * coefA[lo + cc + 3]);
            o.z = pk2(bf2f(gp[4]) * coefA[lo + cc + 4], bf2f(gp[5]) * coefA[lo + cc + 5]);
            o.w = pk2(bf2f(gp[6]) * coefA[lo + cc + 6], bf2f(gp[7]) * coefA[lo + cc + 7]);
            *(uint4*)&Ab[h][cc] = o;
        }
        for (int i = t; i < 512; i += 256) {
            int d = i >> 3, cc = (i & 7) * 8;
            *(uint4*)&Bb[d][cc] =
                *(const uint4*)(ktbf + ((size_t)bn * CHD + d) * CL + lc0 + lo + cc);
        }
        __syncthreads();
#pragma unroll
        for (int mm = 0; mm < 2; ++mm) {
            int m16 = wv * 2 + mm;
#pragma unroll
            for (int n16 = 0; n16 < 4; ++n16)
#pragma unroll
                for (int kk = 0; kk < 2; ++kk) {
                    short8v a = *(const short8v*)&Ab[m16 * 16 + lm][kk * 32 + lg * 8];
                    short8v b = *(const short8v*)&Bb[n16 * 16 + lm][kk * 32 + lg * 8];
                    acc[mm][n16] = MFMA16(a, b, acc[mm][n16]);
                }
        }
    }
    float* og = part + (((size_t)bn * 8 + ks) << 13);
#pragma unroll
    for (int mm = 0; mm < 2; ++mm)
#pragma unroll
        for (int n16 = 0; n16 < 4; ++n16)
#pragma unroll
            for (int r = 0; r < 4; ++r) {
                int h = (wv * 2 + mm) * 16 + lg * 4 + r;
                int d = n16 * 16 + lm;
                og[h * CHD + d] = acc[mm][n16][r];
            }
}

// ---------------------------------------------------------------------------
// W2_next partial (split-K over l).
// ---------------------------------------------------------------------------
__global__ __launch_bounds__(256) void w2n_part(
    const unsigned short* __restrict__ gz2t, const unsigned short* __restrict__ x2t,
    const float* __restrict__ lrp, const float* __restrict__ cump,
    float* __restrict__ part) {
    __shared__ __align__(16) unsigned short Ab[64][72];
    __shared__ __align__(16) unsigned short Bb[128][72];
    __shared__ float coefA[128];
    const int ks = blockIdx.x, bn = blockIdx.y, t = threadIdx.x;
    const int lc0 = ks << 7;
    const int wv = t >> 6, lane = t & 63;
    const int lm = lane & 15, lg = lane >> 4;
    const float cum_last = cump[(size_t)bn * CL + CL - 1];
    if (t < 128)
        coefA[t] = lrp[(size_t)bn * CL + lc0 + t] *
                   __expf(cum_last - cump[(size_t)bn * CL + lc0 + t]);
    f32x4 acc[8];
#pragma unroll
    for (int i = 0; i < 8; ++i) acc[i] = (f32x4){0.f, 0.f, 0.f, 0.f};
    for (int lo = 0; lo < 128; lo += 64) {
        __syncthreads();
        for (int i = t; i < 512; i += 256) {
            int d = i >> 3, cc = (i & 7) * 8;
            uint4 g = *(const uint4*)(gz2t + ((size_t)bn * CHD + d) * CL + lc0 + lo + cc);
            unsigned short* gp = (unsigned short*)&g;
            uint4 o;
            o.x = pk2(bf2f(gp[0]) * coefA[lo + cc + 0], bf2f(gp[1]) * coefA[lo + cc + 1]);
            o.y = pk2(bf2f(gp[2]) * coefA[lo + cc + 2], bf2f(gp[3]) * coefA[lo + cc + 3]);
            o.z = pk2(bf2f(gp[4]) * coefA[lo + cc + 4], bf2f(gp[5]) * coefA[lo + cc + 5]);
            o.w = pk2(bf2f(gp[6]) * coefA[lo + cc + 6], bf2f(gp[7]) * coefA[lo + cc + 7]);
            *(uint4*)&Ab[d][cc] = o;
        }
        for (int i = t; i < 1024; i += 256) {
            int h = i >> 3, cc = (i & 7) * 8;
            *(uint4*)&Bb[h][cc] =
                *(const uint4*)(x2t + ((size_t)bn * CHDH + h) * CL + lc0 + lo + cc);
        }
        __syncthreads();
#pragma unroll
        for (int n16 = 0; n16 < 8; ++n16)
#pragma unroll
            for (int kk = 0; kk < 2; ++kk) {
                short8v a = *(const short8v*)&Ab[wv * 16 + lm][kk * 32 + lg * 8];
                short8v b = *(const short8v*)&Bb[n16 * 16 + lm][kk * 32 + lg * 8];
                acc[n16] = MFMA16(a, b, acc[n16]);
            }
    }
    float* og = part + (((size_t)bn * 8 + ks) << 13);
#pragma unroll
    for (int n16 = 0; n16 < 8; ++n16)
#pragma unroll
        for (int r = 0; r < 4; ++r) {
            int d = wv * 16 + lg * 4 + r;
            int h = n16 * 16 + lm;
            og[d * CHDH + h] = acc[n16][r];
        }
}

// ---------------------------------------------------------------------------
// Reduce partials (fixed order, deterministic).
// ---------------------------------------------------------------------------
__global__ __launch_bounds__(256) void wn_red(
    const float* __restrict__ w1part, const float* __restrict__ w2part,
    const float* __restrict__ W1, const float* __restrict__ W2,
    const float* __restrict__ cump, float* __restrict__ w1n,
    float* __restrict__ w2n) {
    int g = blockIdx.x * 256 + threadIdx.x;  // 0..131071
    const bool isw2 = g >= 65536;
    int e = isw2 ? g - 65536 : g;
    int bn = e >> 11, off = e & 2047;
    const float4* part = (const float4*)(isw2 ? w2part : w1part);
    float4 s = {0.f, 0.f, 0.f, 0.f};
#pragma unroll
    for (int ks = 0; ks < 8; ++ks) {
        float4 v = part[(((size_t)bn * 8 + ks) << 11) + off];
        s.x += v.x; s.y += v.y; s.z += v.z; s.w += v.w;
    }
    const float wdcl = __expf(cump[(size_t)bn * CL + CL - 1]);
    float4 w = ((const float4*)((isw2 ? W2 : W1) + ((size_t)bn << 13)))[off];
    float4 o;
    o.x = wdcl * w.x - s.x;
    o.y = wdcl * w.y - s.y;
    o.z = wdcl * w.z - s.z;
    o.w = wdcl * w.w - s.w;
    ((float4*)((isw2 ? w2n : w1n) + ((size_t)bn << 13)))[off] = o;
}

// ---------------------------------------------------------------------------
extern "C" void kernel_launch(void* const* d_in, const int* in_sizes, int n_in,
                              void* d_out, int out_size, void* d_ws, size_t ws_size,
                              hipStream_t stream) {
    (void)in_sizes; (void)n_in; (void)out_size; (void)ws_size;
    const float* x      = (const float*)d_in[0];
    const float* W1     = (const float*)d_in[1];
    const float* W2     = (const float*)d_in[2];
    const float* lblr   = (const float*)d_in[3];
    const float* fclr_w = (const float*)d_in[4];
    const float* fclr_b = (const float*)d_in[5];
    const float* lbwd   = (const float*)d_in[6];
    const float* fcwd_w = (const float*)d_in[7];
    const float* fcwd_b = (const float*)d_in[8];
    const float* qw = (const float*)d_in[9];
    const float* qb = (const float*)d_in[10];
    const float* kw = (const float*)d_in[11];
    const float* kb = (const float*)d_in[12];
    const float* vw = (const float*)d_in[13];
    const float* vb = (const float*)d_in[14];
    const float* ow = (const float*)d_in[15];
    const float* ob = (const float*)d_in[16];

    float* ws = (float*)d_ws;
    const size_t SZ_HD = (size_t)CBN * CL * CHD;
    const size_t SZ_HDH = (size_t)CBN * CL * CHDH;
    float* qh   = ws;
    float* khb  = qh + SZ_HD;
    float* vhb  = khb + SZ_HD;
    float* gz2b = vhb + SZ_HD;
    float* z2sb = gz2b + SZ_HD;
    float* x2b  = z2sb + SZ_HD;
    float* gz1b = x2b + SZ_HDH;
    float* x2qb = gz1b + SZ_HDH;
    float* lrb  = x2qb + SZ_HDH;
    float* cumb = lrb + (size_t)CBN * CL;
    float* wdcb = cumb + (size_t)CBN * CL;
    unsigned short* xbf  = (unsigned short*)(wdcb + (size_t)CBN * CL);
    unsigned short* qwbf = xbf + (size_t)CB * CL * CD;
    unsigned short* kwbf = qwbf + (size_t)CD * CD;
    unsigned short* vwbf = kwbf + (size_t)CD * CD;
    unsigned short* owh  = vwbf + (size_t)CD * CD;
    unsigned short* owl  = owh + (size_t)CD * CD;

    unsigned short* qbf   = (unsigned short*)qh;
    unsigned short* kbf   = qbf + SZ_HD;
    unsigned short* ktbf  = (unsigned short*)khb;
    unsigned short* w1bf  = ktbf + SZ_HD;
    unsigned short* w2bf  = w1bf + (size_t)CBN * CHDH * CHD;
    unsigned short* w2tbf = w2bf + (size_t)CBN * CHDH * CHD;
    unsigned short* gz2t  = (unsigned short*)gz2b;
    unsigned short* x2t   = (unsigned short*)x2b;
    unsigned short* gz1t  = (unsigned short*)gz1b;
    unsigned short* x2q   = (unsigned short*)x2qb;
    unsigned short* x2bf  = x2q + SZ_HDH;
    float* w1part = qh;
    float* w2part = vhb;

    float* outp = (float*)d_out;
    float* w1n = outp + (size_t)CB * CL * CD;
    float* w2n = w1n + (size_t)CBN * CHDH * CHD;

    tobf_kernel<<<5120, 256, 0, stream>>>(x, qw, kw, vw, xbf, qwbf, kwbf, vwbf);
    tobf2_kernel<<<768, 256, 0, stream>>>(W1, W2, w1bf, w2bf, w2tbf);
    tobf3_kernel<<<1024, 256, 0, stream>>>(ow, owh, owl);
    dim3 gBig(CD / 64, (CB * CL) / 64);
    gemm_bf<0, 1, 0><<<gBig, 256, 0, stream>>>(xbf, qwbf, qb, nullptr, qbf, nullptr);
    gemm_bf<0, 1, 1><<<gBig, 256, 0, stream>>>(xbf, kwbf, kb, nullptr, kbf, ktbf);
    gemm_bf<1, 0, 0><<<gBig, 256, 0, stream>>>(xbf, vwbf, vb, vhb, nullptr, nullptr);
    lrwd_kernel<<<CB * CL, 64, 0, stream>>>(x, lblr, fclr_w, fclr_b, lbwd, fcwd_w,
                                            fcwd_b, lrb, cumb);
    scan_kernel<<<CBN, 64, 0, stream>>>(cumb, wdcb);
    mlp_mfma<<<dim3(CL / 64, CBN), 256, 0, stream>>>(kbf, vhb, w1bf, w2bf, w2tbf,
                                                     x2bf, x2t, gz1t, gz2t);
    attn1_mfma<<<dim3(8, CBN), 512, 0, stream>>>(qbf, kbf, gz1t, w1bf, lrb, cumb,
                                                 wdcb, x2q);
    w1n_part<<<dim3(8, CBN), 256, 0, stream>>>(gz1t, ktbf, lrb, cumb, w1part);
    w2n_part<<<dim3(8, CBN), 256, 0, stream>>>(gz2t, x2t, lrb, cumb, w2part);
    wn_red<<<512, 256, 0, stream>>>(w1part, w2part, W1, W2, cumb, w1n, w2n);
    attn2_mfma<<<dim3(8, CBN), 512, 0, stream>>>(x2q, x2bf, gz2t, w2bf, lrb, cumb,
                                                 wdcb, z2sb);
    gemm_obf<<<gBig, 256, 0, stream>>>(z2sb, owh, owl, ob, outp);
}

// Round 12
// 251.475 us; speedup vs baseline: 1.1297x; 1.1297x over previous
//
#include <hip/hip_runtime.h>

constexpr int CB = 2, CL = 1024, CD = 1024, CNH = 16, CHD = 64, CHDH = 128, CBN = CB * CNH;

__device__ __forceinline__ float sigf(float x) { return 1.0f / (1.0f + __expf(-x)); }

__device__ __forceinline__ unsigned short f2bf(float x) {
    unsigned u = __float_as_uint(x);
    u += 0x7fffu + ((u >> 16) & 1u);
    return (unsigned short)(u >> 16);
}
__device__ __forceinline__ unsigned pk2(float a, float b) {
    return (unsigned)f2bf(a) | ((unsigned)f2bf(b) << 16);
}
__device__ __forceinline__ unsigned pkus(unsigned short a, unsigned short b) {
    return (unsigned)a | ((unsigned)b << 16);
}
__device__ __forceinline__ float bf2f(unsigned short u) {
    return __uint_as_float(((unsigned)u) << 16);
}

typedef __attribute__((ext_vector_type(8))) short short8v;
typedef __attribute__((ext_vector_type(4))) float f32x4;
#define MFMA16(a, b, c) __builtin_amdgcn_mfma_f32_16x16x32_bf16(a, b, c, 0, 0, 0)

// ---------------------------------------------------------------------------
// Merged conversions: x/qw/kw/vw -> bf16; W1/W2/W2^T -> bf16; ow -> hi/lo bf16.
// ---------------------------------------------------------------------------
__global__ __launch_bounds__(256) void conv_kernel(
    const float* __restrict__ x, const float* __restrict__ qw,
    const float* __restrict__ kw, const float* __restrict__ vw,
    const float* __restrict__ W1, const float* __restrict__ W2,
    const float* __restrict__ ow, unsigned short* __restrict__ xb,
    unsigned short* __restrict__ qwb, unsigned short* __restrict__ kwb,
    unsigned short* __restrict__ vwb, unsigned short* __restrict__ w1b,
    unsigned short* __restrict__ w2b, unsigned short* __restrict__ w2t,
    unsigned short* __restrict__ owh, unsigned short* __restrict__ owl) {
    int i = blockIdx.x * 256 + threadIdx.x;  // 0..1769471
    if (i < 1310720) {
        const float* s;
        unsigned short* d;
        int off;
        if (i < 524288) { s = x; d = xb; off = i; }
        else if (i < 786432) { s = qw; d = qwb; off = i - 524288; }
        else if (i < 1048576) { s = kw; d = kwb; off = i - 786432; }
        else { s = vw; d = vwb; off = i - 1048576; }
        float4 v = *(const float4*)(s + (size_t)off * 4);
        *(uint2*)(d + (size_t)off * 4) = make_uint2(pk2(v.x, v.y), pk2(v.z, v.w));
    } else if (i < 1507328) {
        int j = i - 1310720;  // 0..196607
        if (j < 65536) {
            size_t e = (size_t)j * 4;
            float4 v = *(const float4*)(W1 + e);
            *(uint2*)(w1b + e) = make_uint2(pk2(v.x, v.y), pk2(v.z, v.w));
        } else if (j < 131072) {
            size_t e = (size_t)(j - 65536) * 4;
            float4 v = *(const float4*)(W2 + e);
            *(uint2*)(w2b + e) = make_uint2(pk2(v.x, v.y), pk2(v.z, v.w));
        } else {
            size_t e = (size_t)(j - 131072) * 4;
            int bn = (int)(e >> 13), rem = (int)(e & 8191);
            int h = rem >> 6, d0 = rem & 63;
            const float* src = W2 + (size_t)bn * CHD * CHDH;
            float a = src[(d0 + 0) * CHDH + h], b = src[(d0 + 1) * CHDH + h];
            float c = src[(d0 + 2) * CHDH + h], dd = src[(d0 + 3) * CHDH + h];
            *(uint2*)(w2t + e) = make_uint2(pk2(a, b), pk2(c, dd));
        }
    } else {
        size_t e = (size_t)(i - 1507328) * 4;
        float4 v = *(const float4*)(ow + e);
        unsigned short h0 = f2bf(v.x), h1 = f2bf(v.y), h2 = f2bf(v.z), h3 = f2bf(v.w);
        *(uint2*)(owh + e) = make_uint2(pkus(h0, h1), pkus(h2, h3));
        *(uint2*)(owl + e) = make_uint2(
            pk2(v.x - bf2f(h0), v.y - bf2f(h1)), pk2(v.z - bf2f(h2), v.w - bf2f(h3)));
    }
}

// ---------------------------------------------------------------------------
// Merged q/k/v projection GEMM: 128x128 tile, K=1024, 512 threads (8 waves,
// 2m x 4n). A = xbf [2048][1024]; B = wqkv [3072][1024] (qw||kw||vw).
// Epilogue scatters per-head: q -> bf16, k -> bf16 + k^T bf16, v -> fp32.
// ---------------------------------------------------------------------------
__global__ __launch_bounds__(512) void qkv_mfma(
    const unsigned short* __restrict__ xbf, const unsigned short* __restrict__ wqkv,
    const float* __restrict__ qb, const float* __restrict__ kb,
    const float* __restrict__ vb, unsigned short* __restrict__ qbf,
    unsigned short* __restrict__ kbf, unsigned short* __restrict__ ktbf,
    float* __restrict__ vhb) {
    __shared__ __align__(16) unsigned short SH[2][128][72];  // A, B tiles (36.9 KB)
    const int t = threadIdx.x;
    const int c0 = blockIdx.x << 7, r0 = blockIdx.y << 7;
    const int wvid = t >> 6, lane = t & 63;
    const int wm = wvid >> 2, wn = wvid & 3;
    const int lm = lane & 15, lg = lane >> 4;
    f32x4 acc[4][2];
#pragma unroll
    for (int i = 0; i < 4; ++i)
#pragma unroll
        for (int j = 0; j < 2; ++j) acc[i][j] = (f32x4){0.f, 0.f, 0.f, 0.f};
    for (int kc = 0; kc < CD; kc += 64) {
        for (int i = t; i < 1024; i += 512) {
            int r = i >> 3, c = (i & 7) * 8;
            *(uint4*)&SH[0][r][c] = *(const uint4*)(xbf + (size_t)(r0 + r) * CD + kc + c);
            *(uint4*)&SH[1][r][c] = *(const uint4*)(wqkv + (size_t)(c0 + r) * CD + kc + c);
        }
        __syncthreads();
#pragma unroll
        for (int m16 = 0; m16 < 4; ++m16)
#pragma unroll
            for (int n16 = 0; n16 < 2; ++n16)
#pragma unroll
                for (int ks = 0; ks < 2; ++ks) {
                    short8v a = *(const short8v*)&SH[0][wm * 64 + m16 * 16 + lm]
                                                   [ks * 32 + lg * 8];
                    short8v b = *(const short8v*)&SH[1][wn * 32 + n16 * 16 + lm]
                                                   [ks * 32 + lg * 8];
                    acc[m16][n16] = MFMA16(a, b, acc[m16][n16]);
                }
        __syncthreads();
    }
    const int which = c0 >> 10;     // 0=q 1=k 2=v
    const int ccb = c0 & 1023;
    const float* bias = which == 0 ? qb : (which == 1 ? kb : vb);
    const int b = r0 >> 10, lb0 = r0 & 1023;
    float(*Os)[132] = (float(*)[132])SH;  // 64x132 f32 = 33.8 KB overlay
    for (int half = 0; half < 2; ++half) {
        if (wm == half) {
#pragma unroll
            for (int m16 = 0; m16 < 4; ++m16)
#pragma unroll
                for (int n16 = 0; n16 < 2; ++n16) {
                    int col = wn * 32 + n16 * 16 + lm;
                    float bb = bias[ccb + col];
#pragma unroll
                    for (int r = 0; r < 4; ++r)
                        Os[m16 * 16 + lg * 4 + r][col] = acc[m16][n16][r] + bb;
                }
        }
        __syncthreads();
        const int lbase = lb0 + half * 64;
        if (which == 2) {
            for (int i = t; i < 2048; i += 512) {
                int r = i >> 5, c = (i & 31) * 4;
                int n = (ccb + c) >> 6, d = (ccb + c) & 63;
                *(float4*)(vhb + (((size_t)b * CNH + n) * CL + lbase + r) * 64 + d) =
                    *(const float4*)&Os[r][c];
            }
        } else {
            unsigned short* dst = which == 0 ? qbf : kbf;
            for (int i = t; i < 2048; i += 512) {
                int r = i >> 5, c = (i & 31) * 4;
                int n = (ccb + c) >> 6, d = (ccb + c) & 63;
                float4 v4 = *(const float4*)&Os[r][c];
                *(uint2*)(dst + (((size_t)b * CNH + n) * CL + lbase + r) * 64 + d) =
                    make_uint2(pk2(v4.x, v4.y), pk2(v4.z, v4.w));
            }
            if (which == 1) {
                for (int i = t; i < 1024; i += 512) {
                    int col = i >> 3, lb = (i & 7) * 8;
                    int n = (ccb + col) >> 6, d = (ccb + col) & 63;
                    uint4 u;
                    u.x = pk2(Os[lb + 0][col], Os[lb + 1][col]);
                    u.y = pk2(Os[lb + 2][col], Os[lb + 3][col]);
                    u.z = pk2(Os[lb + 4][col], Os[lb + 5][col]);
                    u.w = pk2(Os[lb + 6][col], Os[lb + 7][col]);
                    *(uint4*)(ktbf + (((size_t)b * CNH + n) * 64 + d) * CL + lbase + lb) = u;
                }
            }
        }
        __syncthreads();
    }
}

// ---------------------------------------------------------------------------
// Split-precision MFMA o-projection.
// ---------------------------------------------------------------------------
__global__ __launch_bounds__(256) void gemm_obf(const float* __restrict__ A,
                                                const unsigned short* __restrict__ Bh,
                                                const unsigned short* __restrict__ Bl,
                                                const float* __restrict__ bias,
                                                float* __restrict__ C) {
    __shared__ __align__(16) unsigned short SM[4][64][72];
    const int t = threadIdx.x;
    const int r0 = blockIdx.y << 6, c0 = blockIdx.x << 6;
    const int wv = t >> 6, lane = t & 63;
    const int lm = lane & 15, lg = lane >> 4;
    const int b = r0 >> 10, lb0 = r0 & 1023;
    f32x4 acc[4];
#pragma unroll
    for (int i = 0; i < 4; ++i) acc[i] = (f32x4){0.f, 0.f, 0.f, 0.f};
    for (int kc = 0; kc < CD; kc += 64) {
        for (int i = t; i < 1024; i += 256) {
            int r = i >> 4, c4 = (i & 15) * 4;
            int ak = kc + c4, n = ak >> 6, d = ak & 63;
            float4 v = *(const float4*)(A + ((((size_t)b * CNH + n) * CL + lb0 + r) << 6) + d);
            unsigned short h0 = f2bf(v.x), h1 = f2bf(v.y), h2 = f2bf(v.z), h3 = f2bf(v.w);
            *(uint2*)&SM[0][r][c4] = make_uint2(pkus(h0, h1), pkus(h2, h3));
            *(uint2*)&SM[1][r][c4] = make_uint2(
                pk2(v.x - bf2f(h0), v.y - bf2f(h1)), pk2(v.z - bf2f(h2), v.w - bf2f(h3)));
        }
        for (int i = t; i < 512; i += 256) {
            int r = i >> 3, c = (i & 7) * 8;
            *(uint4*)&SM[2][r][c] = *(const uint4*)(Bh + (size_t)(c0 + r) * CD + kc + c);
            *(uint4*)&SM[3][r][c] = *(const uint4*)(Bl + (size_t)(c0 + r) * CD + kc + c);
        }
        __syncthreads();
#pragma unroll
        for (int n16 = 0; n16 < 4; ++n16)
#pragma unroll
            for (int ks = 0; ks < 2; ++ks) {
                short8v ah = *(const short8v*)&SM[0][wv * 16 + lm][ks * 32 + lg * 8];
                short8v al = *(const short8v*)&SM[1][wv * 16 + lm][ks * 32 + lg * 8];
                short8v bh = *(const short8v*)&SM[2][n16 * 16 + lm][ks * 32 + lg * 8];
                short8v bl = *(const short8v*)&SM[3][n16 * 16 + lm][ks * 32 + lg * 8];
                acc[n16] = MFMA16(ah, bh, acc[n16]);
                acc[n16] = MFMA16(ah, bl, acc[n16]);
                acc[n16] = MFMA16(al, bh, acc[n16]);
            }
        __syncthreads();
    }
    float(*Os)[68] = (float(*)[68])SM;
#pragma unroll
    for (int n16 = 0; n16 < 4; ++n16) {
        float bb = bias[c0 + n16 * 16 + lm];
#pragma unroll
        for (int r = 0; r < 4; ++r)
            Os[wv * 16 + lg * 4 + r][n16 * 16 + lm] = acc[n16][r] + bb;
    }
    __syncthreads();
    for (int i = t; i < 1024; i += 256) {
        int r = i >> 4, c = (i & 15) * 4;
        *(float4*)(C + (size_t)(r0 + r) * CD + c0 + c) = *(const float4*)&Os[r][c];
    }
}

// ---------------------------------------------------------------------------
// lr / log_wd projections.
// ---------------------------------------------------------------------------
__global__ __launch_bounds__(64) void lrwd_kernel(
    const float* __restrict__ x, const float* __restrict__ lblr,
    const float* __restrict__ fclr_w, const float* __restrict__ fclr_b,
    const float* __restrict__ lbwd, const float* __restrict__ fcwd_w,
    const float* __restrict__ fcwd_b, float* __restrict__ lrp,
    float* __restrict__ logwd) {
    const int r = blockIdx.x;
    const int b = r >> 10, l = r & 1023;
    const int lane = threadIdx.x;
    float xv[16];
#pragma unroll
    for (int j = 0; j < 16; ++j) xv[j] = x[(size_t)r * CD + lane + 64 * j];
    for (int n = 0; n < CNH; ++n) {
        float d1 = 0.f, d2 = 0.f;
#pragma unroll
        for (int j = 0; j < 16; ++j) {
            d1 += xv[j] * fclr_w[(size_t)n * CD + lane + 64 * j];
            d2 += xv[j] * fcwd_w[(size_t)n * CD + lane + 64 * j];
        }
#pragma unroll
        for (int s = 32; s > 0; s >>= 1) {
            d1 += __shfl_down(d1, s);
            d2 += __shfl_down(d2, s);
        }
        if (lane == 0) {
            lrp[((size_t)b * CNH + n) * CL + l] = __expf(lblr[n]) * sigf(d1 + fclr_b[n]);
            logwd[((size_t)b * CNH + n) * CL + l] =
                log1pf(-__expf(lbwd[n]) * sigf(d2 + fcwd_b[n]));
        }
    }
}

// ---------------------------------------------------------------------------
// Inclusive prefix sum of log_wd -> cum, plus wdc = exp(cum).
// ---------------------------------------------------------------------------
__global__ __launch_bounds__(64) void scan_kernel(float* __restrict__ cum,
                                                  float* __restrict__ wdc) {
    const int bn = blockIdx.x;
    const int lane = threadIdx.x;
    float* p = cum + (size_t)bn * CL;
    float v[16];
#pragma unroll
    for (int j = 0; j < 16; ++j) v[j] = p[lane * 16 + j];
#pragma unroll
    for (int j = 1; j < 16; ++j) v[j] += v[j - 1];
    float tot = v[15];
    float inc = tot;
#pragma unroll
    for (int s = 1; s < 64; s <<= 1) {
        float tv = __shfl_up(inc, s);
        if (lane >= s) inc += tv;
    }
    const float pre = inc - tot;
#pragma unroll
    for (int j = 0; j < 16; ++j) {
        float c = pre + v[j];
        p[lane * 16 + j] = c;
        wdc[(size_t)bn * CL + lane * 16 + j] = __expf(c);
    }
}

// ---------------------------------------------------------------------------
// MFMA MLP fwd/bwd over 64 tokens.
// ---------------------------------------------------------------------------
__global__ __launch_bounds__(256) void mlp_mfma(
    const unsigned short* __restrict__ kbf, const float* __restrict__ vh,
    const unsigned short* __restrict__ w1bf, const unsigned short* __restrict__ w2bf,
    const unsigned short* __restrict__ w2tbf, unsigned short* __restrict__ x2bf,
    unsigned short* __restrict__ x2t, unsigned short* __restrict__ gz1t,
    unsigned short* __restrict__ gz2t) {
    __shared__ __align__(16) unsigned short RA[128][72];
    __shared__ __align__(16) unsigned short RB[64][72];
    __shared__ __align__(16) unsigned short RC[64][136];
    __shared__ __align__(16) unsigned short X2s[64][136];
    const int bn = blockIdx.y, l0 = blockIdx.x << 6;
    const int t = threadIdx.x;
    const int wv = t >> 6, lane = t & 63;
    const int lm = lane & 15, lg = lane >> 4;
    {
        const unsigned short* kg = kbf + ((size_t)bn * CL + l0) * CHD;
        for (int i = t; i < 512; i += 256) {
            int r = i >> 3, c = (i & 7) * 8;
            *(uint4*)&RB[r][c] = *(const uint4*)(kg + (size_t)r * CHD + c);
        }
        const unsigned short* w1g = w1bf + (size_t)bn * CHDH * CHD;
        for (int i = t; i < 1024; i += 256) {
            int r = i >> 3, c = (i & 7) * 8;
            *(uint4*)&RA[r][c] = *(const uint4*)(w1g + (size_t)r * CHD + c);
        }
        const unsigned short* w2g = w2bf + (size_t)bn * CHD * CHDH;
        for (int i = t; i < 1024; i += 256) {
            int r = i >> 4, c = (i & 15) * 8;
            *(uint4*)&RC[r][c] = *(const uint4*)(w2g + (size_t)r * CHDH + c);
        }
    }
    __syncthreads();
    f32x4 acc1[4][2];
#pragma unroll
    for (int i = 0; i < 4; ++i)
#pragma unroll
        for (int j = 0; j < 2; ++j) acc1[i][j] = (f32x4){0.f, 0.f, 0.f, 0.f};
#pragma unroll
    for (int m16 = 0; m16 < 4; ++m16)
#pragma unroll
        for (int hh = 0; hh < 2; ++hh) {
            int h16 = wv * 2 + hh;
#pragma unroll
            for (int ks = 0; ks < 2; ++ks) {
                short8v a = *(const short8v*)&RB[m16 * 16 + lm][ks * 32 + lg * 8];
                short8v b = *(const short8v*)&RA[h16 * 16 + lm][ks * 32 + lg * 8];
                acc1[m16][hh] = MFMA16(a, b, acc1[m16][hh]);
            }
        }
#pragma unroll
    for (int m16 = 0; m16 < 4; ++m16)
#pragma unroll
        for (int hh = 0; hh < 2; ++hh)
#pragma unroll
            for (int r = 0; r < 4; ++r) {
                float a = acc1[m16][hh][r];
                X2s[m16 * 16 + lg * 4 + r][(wv * 2 + hh) * 16 + lm] = f2bf(a * sigf(a));
            }
    __syncthreads();
    {
        const unsigned short* w2tg = w2tbf + (size_t)bn * CHDH * CHD;
        for (int i = t; i < 1024; i += 256) {
            int r = i >> 3, c = (i & 7) * 8;
            *(uint4*)&RA[r][c] = *(const uint4*)(w2tg + (size_t)r * CHD + c);
        }
    }
    {
        f32x4 acc2[4];
#pragma unroll
        for (int i = 0; i < 4; ++i) acc2[i] = (f32x4){0.f, 0.f, 0.f, 0.f};
#pragma unroll
        for (int m16 = 0; m16 < 4; ++m16)
#pragma unroll
            for (int ks = 0; ks < 4; ++ks) {
                short8v a = *(const short8v*)&X2s[m16 * 16 + lm][ks * 32 + lg * 8];
                short8v b = *(const short8v*)&RC[wv * 16 + lm][ks * 32 + lg * 8];
                acc2[m16] = MFMA16(a, b, acc2[m16]);
            }
#pragma unroll
        for (int m16 = 0; m16 < 4; ++m16)
#pragma unroll
            for (int r = 0; r < 4; ++r) {
                int l = l0 + m16 * 16 + lg * 4 + r;
                float v = vh[((size_t)bn * CL + l) * 64 + wv * 16 + lm];
                RB[m16 * 16 + lg * 4 + r][wv * 16 + lm] = f2bf(acc2[m16][r] - v);
            }
    }
    __syncthreads();
#pragma unroll
    for (int m16 = 0; m16 < 4; ++m16)
#pragma unroll
        for (int hh = 0; hh < 2; ++hh) {
            int h16 = wv * 2 + hh;
            f32x4 p = (f32x4){0.f, 0.f, 0.f, 0.f};
#pragma unroll
            for (int ks = 0; ks < 2; ++ks) {
                short8v a = *(const short8v*)&RB[m16 * 16 + lm][ks * 32 + lg * 8];
                short8v b = *(const short8v*)&RA[h16 * 16 + lm][ks * 32 + lg * 8];
                p = MFMA16(a, b, p);
            }
#pragma unroll
            for (int r = 0; r < 4; ++r) {
                float zz = acc1[m16][hh][r];
                float s = sigf(zz);
                float sil = zz * s;
                RC[m16 * 16 + lg * 4 + r][h16 * 16 + lm] =
                    f2bf((sil + s * (1.f - sil)) * p[r]);
            }
        }
    __syncthreads();
    for (int i = t; i < 1024; i += 256) {
        int r = i >> 4, c = (i & 15) * 8;
        *(uint4*)(x2bf + ((size_t)bn * CL + l0 + r) * CHDH + c) = *(const uint4*)&X2s[r][c];
    }
    for (int i = t; i < 1024; i += 256) {
        int h = i >> 3, lb = (i & 7) * 8;
        uint4 u;
        u.x = pkus(X2s[lb + 0][h], X2s[lb + 1][h]);
        u.y = pkus(X2s[lb + 2][h], X2s[lb + 3][h]);
        u.z = pkus(X2s[lb + 4][h], X2s[lb + 5][h]);
        u.w = pkus(X2s[lb + 6][h], X2s[lb + 7][h]);
        *(uint4*)(x2t + ((size_t)bn * CHDH + h) * CL + l0 + lb) = u;
    }
    for (int i = t; i < 1024; i += 256) {
        int h = i >> 3, lb = (i & 7) * 8;
        uint4 u;
        u.x = pkus(RC[lb + 0][h], RC[lb + 1][h]);
        u.y = pkus(RC[lb + 2][h], RC[lb + 3][h]);
        u.z = pkus(RC[lb + 4][h], RC[lb + 5][h]);
        u.w = pkus(RC[lb + 6][h], RC[lb + 7][h]);
        *(uint4*)(gz1t + ((size_t)bn * CHDH + h) * CL + l0 + lb) = u;
    }
    for (int i = t; i < 512; i += 256) {
        int d = i >> 3, lb = (i & 7) * 8;
        uint4 u;
        u.x = pkus(RB[lb + 0][d], RB[lb + 1][d]);
        u.y = pkus(RB[lb + 2][d], RB[lb + 3][d]);
        u.z = pkus(RB[lb + 4][d], RB[lb + 5][d]);
        u.w = pkus(RB[lb + 6][d], RB[lb + 7][d]);
        *(uint4*)(gz2t + ((size_t)bn * CHD + d) * CL + l0 + lb) = u;
    }
}

// ---------------------------------------------------------------------------
// attn1 (MFMA bf16, paired m-tiles, XCD-swizzled, register-cached fragments).
// ---------------------------------------------------------------------------
__global__ __launch_bounds__(512) void attn1_mfma(
    const unsigned short* __restrict__ qbf, const unsigned short* __restrict__ kbf,
    const unsigned short* __restrict__ gz1t, const unsigned short* __restrict__ w1bf,
    const float* __restrict__ lrp, const float* __restrict__ cump,
    const float* __restrict__ wdcp, unsigned short* __restrict__ x2q) {
    __shared__ __align__(16) unsigned short SH[32256];
    __shared__ float lrl[64], cuml[64], cumm[128], wdcm[128];
    unsigned short(*Qb)[72] = (unsigned short(*)[72])SH;
    unsigned short(*Kb)[72] = (unsigned short(*)[72])(SH + 9216);
    unsigned short(*GT)[72] = (unsigned short(*)[72])(SH + 13824);
    unsigned short(*Pm)[72] = (unsigned short(*)[72])(SH + 23040);
    const int bx = blockIdx.x, by = blockIdx.y;
    const int bn = (bx << 2) + (by >> 3);  // XCD swizzle
    const int p = by & 7;
    const int mtB = 15 - p;
    const int m0A = p << 6, m0B = mtB << 6;
    const int t = threadIdx.x;
    const int wv = t >> 6, lane = t & 63;
    const int grp = wv >> 2, w4 = wv & 3;
    const int lm = lane & 15, lg = lane >> 4;
    const int qbase = grp << 6;
    const int m0 = grp ? m0B : m0A;
    const int mtsel = grp ? mtB : p;
    const int sr = t >> 3, sc = (t & 7) * 8;
    uint4 pkv, pgv[2];
    float plr, pcu;
    {
        const unsigned short* kg = kbf + (size_t)bn * CL * CHD;
        pkv = *(const uint4*)(kg + (size_t)sr * CHD + sc);
        const unsigned short* gg = gz1t + (size_t)bn * CHDH * CL;
        pgv[0] = *(const uint4*)(gg + (size_t)sr * CL + sc);
        pgv[1] = *(const uint4*)(gg + (size_t)(sr + 64) * CL + sc);
        if (t < 64) {
            plr = lrp[(size_t)bn * CL + t];
            pcu = cump[(size_t)bn * CL + t];
        }
    }
    {
        const unsigned short* qgA = qbf + ((size_t)bn * CL + m0A) * CHD;
        const unsigned short* qgB = qbf + ((size_t)bn * CL + m0B) * CHD;
        *(uint4*)&Qb[sr][sc] = *(const uint4*)(qgA + (size_t)sr * CHD + sc);
        *(uint4*)&Qb[64 + sr][sc] = *(const uint4*)(qgB + (size_t)sr * CHD + sc);
        const unsigned short* wg = w1bf + (size_t)bn * CHDH * CHD;
        *(uint4*)&GT[sr][sc] = *(const uint4*)(wg + (size_t)sr * CHD + sc);
        *(uint4*)&GT[64 + sr][sc] = *(const uint4*)(wg + (size_t)(sr + 64) * CHD + sc);
        if (t < 128) {
            int mm = (t < 64) ? (m0A + t) : (m0B + t - 64);
            cumm[t] = cump[(size_t)bn * CL + mm];
            wdcm[t] = wdcp[(size_t)bn * CL + mm];
        }
    }
    __syncthreads();
    short8v qf[4][2];
#pragma unroll
    for (int m16 = 0; m16 < 4; ++m16)
#pragma unroll
        for (int ks = 0; ks < 2; ++ks)
            qf[m16][ks] = *(const short8v*)&Qb[qbase + m16 * 16 + lm][ks * 32 + lg * 8];
    f32x4 acc[4][2];
#pragma unroll
    for (int i = 0; i < 4; ++i)
#pragma unroll
        for (int j = 0; j < 2; ++j) acc[i][j] = (f32x4){0.f, 0.f, 0.f, 0.f};
    {
        short8v wf[2][2];
#pragma unroll
        for (int hh = 0; hh < 2; ++hh)
#pragma unroll
            for (int ks = 0; ks < 2; ++ks)
                wf[hh][ks] =
                    *(const short8v*)&GT[(w4 * 2 + hh) * 16 + lm][ks * 32 + lg * 8];
#pragma unroll
        for (int m16 = 0; m16 < 4; ++m16)
#pragma unroll
            for (int hh = 0; hh < 2; ++hh)
#pragma unroll
                for (int ks = 0; ks < 2; ++ks)
                    acc[m16][hh] = MFMA16(qf[m16][ks], wf[hh][ks], acc[m16][hh]);
    }
#pragma unroll
    for (int m16 = 0; m16 < 4; ++m16) {
#pragma unroll
        for (int r = 0; r < 4; ++r) {
            float w = wdcm[qbase + m16 * 16 + lg * 4 + r];
            acc[m16][0][r] *= w;
            acc[m16][1][r] *= w;
        }
    }
    __syncthreads();
    for (int lt = 0; lt <= mtB; ++lt) {
        const int l0 = lt << 6;
        *(uint4*)&Kb[sr][sc] = pkv;
        *(uint4*)&GT[sr][sc] = pgv[0];
        *(uint4*)&GT[64 + sr][sc] = pgv[1];
        if (t < 64) {
            lrl[t] = plr;
            cuml[t] = pcu;
        }
        __syncthreads();
        if (lt < mtB) {
            const int ln = l0 + 64;
            const unsigned short* kg = kbf + ((size_t)bn * CL + ln) * CHD;
            pkv = *(const uint4*)(kg + (size_t)sr * CHD + sc);
            const unsigned short* gg = gz1t + (size_t)bn * CHDH * CL + ln;
            pgv[0] = *(const uint4*)(gg + (size_t)sr * CL + sc);
            pgv[1] = *(const uint4*)(gg + (size_t)(sr + 64) * CL + sc);
            if (t < 64) {
                plr = lrp[(size_t)bn * CL + ln + t];
                pcu = cump[(size_t)bn * CL + ln + t];
            }
        }
        const bool active = (lt <= mtsel);
        if (active) {
            short8v kf[2];
#pragma unroll
            for (int ks = 0; ks < 2; ++ks)
                kf[ks] = *(const short8v*)&Kb[w4 * 16 + lm][ks * 32 + lg * 8];
#pragma unroll
            for (int m16 = 0; m16 < 4; ++m16) {
                f32x4 s = (f32x4){0.f, 0.f, 0.f, 0.f};
#pragma unroll
                for (int ks = 0; ks < 2; ++ks) s = MFMA16(kf[ks], qf[m16][ks], s);
                int mloc = m16 * 16 + lm;
                int mabs = m0 + mloc;
                float cm = cumm[qbase + mloc];
                unsigned short pv[4];
#pragma unroll
                for (int r = 0; r < 4; ++r) {
                    int lloc = w4 * 16 + lg * 4 + r;
                    float val = (mabs >= l0 + lloc)
                                    ? s[r] * lrl[lloc] * __expf(cm - cuml[lloc])
                                    : 0.f;
                    pv[r] = f2bf(val);
                }
                *(uint2*)&Pm[qbase + mloc][w4 * 16 + lg * 4] =
                    make_uint2(pkus(pv[0], pv[1]), pkus(pv[2], pv[3]));
            }
        }
        __syncthreads();
        if (active) {
            short8v gt[2][2], pm[4][2];
#pragma unroll
            for (int hh = 0; hh < 2; ++hh)
#pragma unroll
                for (int ks = 0; ks < 2; ++ks)
                    gt[hh][ks] =
                        *(const short8v*)&GT[(w4 * 2 + hh) * 16 + lm][ks * 32 + lg * 8];
#pragma unroll
            for (int m16 = 0; m16 < 4; ++m16)
#pragma unroll
                for (int ks = 0; ks < 2; ++ks)
                    pm[m16][ks] = *(const short8v*)&Pm[qbase + m16 * 16 + lm]
                                                     [ks * 32 + lg * 8];
#pragma unroll
            for (int m16 = 0; m16 < 4; ++m16)
#pragma unroll
                for (int hh = 0; hh < 2; ++hh) {
                    f32x4 pf = (f32x4){0.f, 0.f, 0.f, 0.f};
#pragma unroll
                    for (int ks = 0; ks < 2; ++ks)
                        pf = MFMA16(pm[m16][ks], gt[hh][ks], pf);
#pragma unroll
                    for (int r = 0; r < 4; ++r) acc[m16][hh][r] -= pf[r];
                }
        }
        __syncthreads();
    }
    {
        unsigned short(*Ob)[136] = (unsigned short(*)[136])SH;
#pragma unroll
        for (int m16 = 0; m16 < 4; ++m16)
#pragma unroll
            for (int hh = 0; hh < 2; ++hh) {
                int h = (w4 * 2 + hh) * 16 + lm;
#pragma unroll
                for (int r = 0; r < 4; ++r) {
                    int mloc = m16 * 16 + lg * 4 + r;
                    float a = acc[m16][hh][r];
                    Ob[qbase + mloc][h] = f2bf(a * sigf(a));
                }
            }
        __syncthreads();
        unsigned short* og = x2q + (size_t)bn * CL * CHDH;
        for (int i = t; i < 2048; i += 512) {
            int r = i >> 4, c = (i & 15) * 8;
            int gm = (r < 64) ? (m0A + r) : (m0B + r - 64);
            *(uint4*)(og + (size_t)gm * CHDH + c) = *(const uint4*)&Ob[r][c];
        }
    }
}

// ---------------------------------------------------------------------------
// attn2 (MFMA bf16, paired m-tiles, XCD-swizzled, register-cached fragments).
// ---------------------------------------------------------------------------
__global__ __launch_bounds__(512) void attn2_mfma(
    const unsigned short* __restrict__ x2q, const unsigned short* __restrict__ x2bf,
    const unsigned short* __restrict__ gz2t, const unsigned short* __restrict__ w2bf,
    const float* __restrict__ lrp, const float* __restrict__ cump,
    const float* __restrict__ wdcp, float* __restrict__ z2s) {
    __shared__ __align__(16) unsigned short SH[39936];
    __shared__ float lrl[64], cuml[64], cumm[128], wdcm[128];
    unsigned short(*X2qb)[136] = (unsigned short(*)[136])SH;
    unsigned short(*X2l)[136] = (unsigned short(*)[136])(SH + 17408);
    unsigned short(*GT2)[72] = (unsigned short(*)[72])(SH + 26112);
    unsigned short(*Pm)[72] = (unsigned short(*)[72])(SH + 30720);
    const int bx = blockIdx.x, by = blockIdx.y;
    const int bn = (bx << 2) + (by >> 3);  // XCD swizzle
    const int p = by & 7;
    const int mtB = 15 - p;
    const int m0A = p << 6, m0B = mtB << 6;
    const int t = threadIdx.x;
    const int wv = t >> 6, lane = t & 63;
    const int grp = wv >> 2, w4 = wv & 3;
    const int lm = lane & 15, lg = lane >> 4;
    const int qbase = grp << 6;
    const int m0 = grp ? m0B : m0A;
    const int mtsel = grp ? mtB : p;
    const int xr = t >> 4, xc = (t & 15) * 8;
    const int gr = t >> 3, gc = (t & 7) * 8;
    uint4 px[2], pgv;
    float plr, pcu;
    {
        const unsigned short* kg = x2bf + (size_t)bn * CL * CHDH;
        px[0] = *(const uint4*)(kg + (size_t)xr * CHDH + xc);
        px[1] = *(const uint4*)(kg + (size_t)(xr + 32) * CHDH + xc);
        const unsigned short* gg = gz2t + (size_t)bn * CHD * CL;
        pgv = *(const uint4*)(gg + (size_t)gr * CL + gc);
        if (t < 64) {
            plr = lrp[(size_t)bn * CL + t];
            pcu = cump[(size_t)bn * CL + t];
        }
    }
    {
        const unsigned short* qgA = x2q + ((size_t)bn * CL + m0A) * CHDH;
        const unsigned short* qgB = x2q + ((size_t)bn * CL + m0B) * CHDH;
        *(uint4*)&X2qb[xr][xc] = *(const uint4*)(qgA + (size_t)xr * CHDH + xc);
        *(uint4*)&X2qb[xr + 32][xc] = *(const uint4*)(qgA + (size_t)(xr + 32) * CHDH + xc);
        *(uint4*)&X2qb[xr + 64][xc] = *(const uint4*)(qgB + (size_t)xr * CHDH + xc);
        *(uint4*)&X2qb[xr + 96][xc] = *(const uint4*)(qgB + (size_t)(xr + 32) * CHDH + xc);
        const unsigned short* wg = w2bf + (size_t)bn * CHD * CHDH;
        *(uint4*)&X2l[xr][xc] = *(const uint4*)(wg + (size_t)xr * CHDH + xc);
        *(uint4*)&X2l[xr + 32][xc] = *(const uint4*)(wg + (size_t)(xr + 32) * CHDH + xc);
        if (t < 128) {
            int mm = (t < 64) ? (m0A + t) : (m0B + t - 64);
            cumm[t] = cump[(size_t)bn * CL + mm];
            wdcm[t] = wdcp[(size_t)bn * CL + mm];
        }
    }
    __syncthreads();
    short8v qf[4][4];
#pragma unroll
    for (int m16 = 0; m16 < 4; ++m16)
#pragma unroll
        for (int ks = 0; ks < 4; ++ks)
            qf[m16][ks] =
                *(const short8v*)&X2qb[qbase + m16 * 16 + lm][ks * 32 + lg * 8];
    f32x4 acc[4];
#pragma unroll
    for (int i = 0; i < 4; ++i) acc[i] = (f32x4){0.f, 0.f, 0.f, 0.f};
    {
        short8v wf[4];
#pragma unroll
        for (int ks = 0; ks < 4; ++ks)
            wf[ks] = *(const short8v*)&X2l[w4 * 16 + lm][ks * 32 + lg * 8];
#pragma unroll
        for (int m16 = 0; m16 < 4; ++m16)
#pragma unroll
            for (int ks = 0; ks < 4; ++ks)
                acc[m16] = MFMA16(qf[m16][ks], wf[ks], acc[m16]);
    }
#pragma unroll
    for (int m16 = 0; m16 < 4; ++m16)
#pragma unroll
        for (int r = 0; r < 4; ++r) acc[m16][r] *= wdcm[qbase + m16 * 16 + lg * 4 + r];
    __syncthreads();
    for (int lt = 0; lt <= mtB; ++lt) {
        const int l0 = lt << 6;
        *(uint4*)&X2l[xr][xc] = px[0];
        *(uint4*)&X2l[xr + 32][xc] = px[1];
        *(uint4*)&GT2[gr][gc] = pgv;
        if (t < 64) {
            lrl[t] = plr;
            cuml[t] = pcu;
        }
        __syncthreads();
        if (lt < mtB) {
            const int ln = l0 + 64;
            const unsigned short* kg = x2bf + ((size_t)bn * CL + ln) * CHDH;
            px[0] = *(const uint4*)(kg + (size_t)xr * CHDH + xc);
            px[1] = *(const uint4*)(kg + (size_t)(xr + 32) * CHDH + xc);
            const unsigned short* gg = gz2t + (size_t)bn * CHD * CL + ln;
            pgv = *(const uint4*)(gg + (size_t)gr * CL + gc);
            if (t < 64) {
                plr = lrp[(size_t)bn * CL + ln + t];
                pcu = cump[(size_t)bn * CL + ln + t];
            }
        }
        const bool active = (lt <= mtsel);
        if (active) {
            short8v kf[4];
#pragma unroll
            for (int ks = 0; ks < 4; ++ks)
                kf[ks] = *(const short8v*)&X2l[w4 * 16 + lm][ks * 32 + lg * 8];
#pragma unroll
            for (int m16 = 0; m16 < 4; ++m16) {
                f32x4 s = (f32x4){0.f, 0.f, 0.f, 0.f};
#pragma unroll
                for (int ks = 0; ks < 4; ++ks) s = MFMA16(kf[ks], qf[m16][ks], s);
                int mloc = m16 * 16 + lm;
                int mabs = m0 + mloc;
                float cm = cumm[qbase + mloc];
                unsigned short pv[4];
#pragma unroll
                for (int r = 0; r < 4; ++r) {
                    int lloc = w4 * 16 + lg * 4 + r;
                    float val = (mabs >= l0 + lloc)
                                    ? s[r] * lrl[lloc] * __expf(cm - cuml[lloc])
                                    : 0.f;
                    pv[r] = f2bf(val);
                }
                *(uint2*)&Pm[qbase + mloc][w4 * 16 + lg * 4] =
                    make_uint2(pkus(pv[0], pv[1]), pkus(pv[2], pv[3]));
            }
        }
        __syncthreads();
        if (active) {
            short8v gt[2], pm[4][2];
#pragma unroll
            for (int ks = 0; ks < 2; ++ks)
                gt[ks] = *(const short8v*)&GT2[w4 * 16 + lm][ks * 32 + lg * 8];
#pragma unroll
            for (int m16 = 0; m16 < 4; ++m16)
#pragma unroll
                for (int ks = 0; ks < 2; ++ks)
                    pm[m16][ks] = *(const short8v*)&Pm[qbase + m16 * 16 + lm]
                                                     [ks * 32 + lg * 8];
#pragma unroll
            for (int m16 = 0; m16 < 4; ++m16) {
                f32x4 pf = (f32x4){0.f, 0.f, 0.f, 0.f};
#pragma unroll
                for (int ks = 0; ks < 2; ++ks) pf = MFMA16(pm[m16][ks], gt[ks], pf);
#pragma unroll
                for (int r = 0; r < 4; ++r) acc[m16][r] -= pf[r];
            }
        }
        __syncthreads();
    }
    {
        float(*Os)[68] = (float(*)[68])SH;
#pragma unroll
        for (int m16 = 0; m16 < 4; ++m16)
#pragma unroll
            for (int r = 0; r < 4; ++r)
                Os[qbase + m16 * 16 + lg * 4 + r][w4 * 16 + lm] = acc[m16][r];
        __syncthreads();
        float* zg = z2s + (size_t)bn * CL * CHD;
        for (int i = t; i < 2048; i += 512) {
            int r = i >> 4, c = (i & 15) << 2;
            int gm = (r < 64) ? (m0A + r) : (m0B + r - 64);
            *(float4*)(zg + (size_t)gm * CHD + c) = *(const float4*)&Os[r][c];
        }
    }
}

// ---------------------------------------------------------------------------
// W1_next partial (split-K over l).
// ---------------------------------------------------------------------------
__global__ __launch_bounds__(256) void w1n_part(
    const unsigned short* __restrict__ gz1t, const unsigned short* __restrict__ ktbf,
    const float* __restrict__ lrp, const float* __restrict__ cump,
    float* __restrict__ part) {
    __shared__ __align__(16) unsigned short Ab[128][72];
    __shared__ __align__(16) unsigned short Bb[64][72];
    __shared__ float coefA[128];
    const int ks = blockIdx.x, bn = blockIdx.y, t = threadIdx.x;
    const int lc0 = ks << 7;
    const int wv = t >> 6, lane = t & 63;
    const int lm = lane & 15, lg = lane >> 4;
    const float cum_last = cump[(size_t)bn * CL + CL - 1];
    if (t < 128)
        coefA[t] = lrp[(size_t)bn * CL + lc0 + t] *
                   __expf(cum_last - cump[(size_t)bn * CL + lc0 + t]);
    f32x4 acc[2][4];
#pragma unroll
    for (int i = 0; i < 2; ++i)
#pragma unroll
        for (int j = 0; j < 4; ++j) acc[i][j] = (f32x4){0.f, 0.f, 0.f, 0.f};
    for (int lo = 0; lo < 128; lo += 64) {
        __syncthreads();
        for (int i = t; i < 1024; i += 256) {
            int h = i >> 3, cc = (i & 7) * 8;
            uint4 g = *(const uint4*)(gz1t + ((size_t)bn * CHDH + h) * CL + lc0 + lo + cc);
            unsigned short* gp = (unsigned short*)&g;
            uint4 o;
            o.x = pk2(bf2f(gp[0]) * coefA[lo + cc + 0], bf2f(gp[1]) * coefA[lo + cc + 1]);
            o.y = pk2(bf2f(gp[2]) * coefA[lo + cc + 2], bf2f(gp[3]) * coefA[lo + cc + 3]);
            o.z = pk2(bf2f(gp[4]) * coefA[lo + cc + 4], bf2f(gp[5]) * coefA[lo + cc + 5]);
            o.w = pk2(bf2f(gp[6]) * coefA[lo + cc + 6], bf2f(gp[7]) * coefA[lo + cc + 7]);
            *(uint4*)&Ab[h][cc] = o;
        }
        for (int i = t; i < 512; i += 256) {
            int d = i >> 3, cc = (i & 7) * 8;
            *(uint4*)&Bb[d][cc] =
                *(const uint4*)(ktbf + ((size_t)bn * CHD + d) * CL + lc0 + lo + cc);
        }
        __syncthreads();
#pragma unroll
        for (int mm = 0; mm < 2; ++mm) {
            int m16 = wv * 2 + mm;
#pragma unroll
            for (int n16 = 0; n16 < 4; ++n16)
#pragma unroll
                for (int kk = 0; kk < 2; ++kk) {
                    short8v a = *(const short8v*)&Ab[m16 * 16 + lm][kk * 32 + lg * 8];
                    short8v b = *(const short8v*)&Bb[n16 * 16 + lm][kk * 32 + lg * 8];
                    acc[mm][n16] = MFMA16(a, b, acc[mm][n16]);
                }
        }
    }
    float* og = part + (((size_t)bn * 8 + ks) << 13);
#pragma unroll
    for (int mm = 0; mm < 2; ++mm)
#pragma unroll
        for (int n16 = 0; n16 < 4; ++n16)
#pragma unroll
            for (int r = 0; r < 4; ++r) {
                int h = (wv * 2 + mm) * 16 + lg * 4 + r;
                int d = n16 * 16 + lm;
                og[h * CHD + d] = acc[mm][n16][r];
            }
}

// ---------------------------------------------------------------------------
// W2_next partial (split-K over l).
// ---------------------------------------------------------------------------
__global__ __launch_bounds__(256) void w2n_part(
    const unsigned short* __restrict__ gz2t, const unsigned short* __restrict__ x2t,
    const float* __restrict__ lrp, const float* __restrict__ cump,
    float* __restrict__ part) {
    __shared__ __align__(16) unsigned short Ab[64][72];
    __shared__ __align__(16) unsigned short Bb[128][72];
    __shared__ float coefA[128];
    const int ks = blockIdx.x, bn = blockIdx.y, t = threadIdx.x;
    const int lc0 = ks << 7;
    const int wv = t >> 6, lane = t & 63;
    const int lm = lane & 15, lg = lane >> 4;
    const float cum_last = cump[(size_t)bn * CL + CL - 1];
    if (t < 128)
        coefA[t] = lrp[(size_t)bn * CL + lc0 + t] *
                   __expf(cum_last - cump[(size_t)bn * CL + lc0 + t]);
    f32x4 acc[8];
#pragma unroll
    for (int i = 0; i < 8; ++i) acc[i] = (f32x4){0.f, 0.f, 0.f, 0.f};
    for (int lo = 0; lo < 128; lo += 64) {
        __syncthreads();
        for (int i = t; i < 512; i += 256) {
            int d = i >> 3, cc = (i & 7) * 8;
            uint4 g = *(const uint4*)(gz2t + ((size_t)bn * CHD + d) * CL + lc0 + lo + cc);
            unsigned short* gp = (unsigned short*)&g;
            uint4 o;
            o.x = pk2(bf2f(gp[0]) * coefA[lo + cc + 0], bf2f(gp[1]) * coefA[lo + cc + 1]);
            o.y = pk2(bf2f(gp[2]) * coefA[lo + cc + 2], bf2f(gp[3]) * coefA[lo + cc + 3]);
            o.z = pk2(bf2f(gp[4]) * coefA[lo + cc + 4], bf2f(gp[5]) * coefA[lo + cc + 5]);
            o.w = pk2(bf2f(gp[6]) * coefA[lo + cc + 6], bf2f(gp[7]) * coefA[lo + cc + 7]);
            *(uint4*)&Ab[d][cc] = o;
        }
        for (int i = t; i < 1024; i += 256) {
            int h = i >> 3, cc = (i & 7) * 8;
            *(uint4*)&Bb[h][cc] =
                *(const uint4*)(x2t + ((size_t)bn * CHDH + h) * CL + lc0 + lo + cc);
        }
        __syncthreads();
#pragma unroll
        for (int n16 = 0; n16 < 8; ++n16)
#pragma unroll
            for (int kk = 0; kk < 2; ++kk) {
                short8v a = *(const short8v*)&Ab[wv * 16 + lm][kk * 32 + lg * 8];
                short8v b = *(const short8v*)&Bb[n16 * 16 + lm][kk * 32 + lg * 8];
                acc[n16] = MFMA16(a, b, acc[n16]);
            }
    }
    float* og = part + (((size_t)bn * 8 + ks) << 13);
#pragma unroll
    for (int n16 = 0; n16 < 8; ++n16)
#pragma unroll
        for (int r = 0; r < 4; ++r) {
            int d = wv * 16 + lg * 4 + r;
            int h = n16 * 16 + lm;
            og[d * CHDH + h] = acc[n16][r];
        }
}

// ---------------------------------------------------------------------------
// Reduce partials (fixed order, deterministic).
// ---------------------------------------------------------------------------
__global__ __launch_bounds__(256) void wn_red(
    const float* __restrict__ w1part, const float* __restrict__ w2part,
    const float* __restrict__ W1, const float* __restrict__ W2,
    const float* __restrict__ cump, float* __restrict__ w1n,
    float* __restrict__ w2n) {
    int g = blockIdx.x * 256 + threadIdx.x;  // 0..131071
    const bool isw2 = g >= 65536;
    int e = isw2 ? g - 65536 : g;
    int bn = e >> 11, off = e & 2047;
    const float4* part = (const float4*)(isw2 ? w2part : w1part);
    float4 s = {0.f, 0.f, 0.f, 0.f};
#pragma unroll
    for (int ks = 0; ks < 8; ++ks) {
        float4 v = part[(((size_t)bn * 8 + ks) << 11) + off];
        s.x += v.x; s.y += v.y; s.z += v.z; s.w += v.w;
    }
    const float wdcl = __expf(cump[(size_t)bn * CL + CL - 1]);
    float4 w = ((const float4*)((isw2 ? W2 : W1) + ((size_t)bn << 13)))[off];
    float4 o;
    o.x = wdcl * w.x - s.x;
    o.y = wdcl * w.y - s.y;
    o.z = wdcl * w.z - s.z;
    o.w = wdcl * w.w - s.w;
    ((float4*)((isw2 ? w2n : w1n) + ((size_t)bn << 13)))[off] = o;
}

// ---------------------------------------------------------------------------
extern "C" void kernel_launch(void* const* d_in, const int* in_sizes, int n_in,
                              void* d_out, int out_size, void* d_ws, size_t ws_size,
                              hipStream_t stream) {
    (void)in_sizes; (void)n_in; (void)out_size; (void)ws_size;
    const float* x      = (const float*)d_in[0];
    const float* W1     = (const float*)d_in[1];
    const float* W2     = (const float*)d_in[2];
    const float* lblr   = (const float*)d_in[3];
    const float* fclr_w = (const float*)d_in[4];
    const float* fclr_b = (const float*)d_in[5];
    const float* lbwd   = (const float*)d_in[6];
    const float* fcwd_w = (const float*)d_in[7];
    const float* fcwd_b = (const float*)d_in[8];
    const float* qw = (const float*)d_in[9];
    const float* qb = (const float*)d_in[10];
    const float* kw = (const float*)d_in[11];
    const float* kb = (const float*)d_in[12];
    const float* vw = (const float*)d_in[13];
    const float* vb = (const float*)d_in[14];
    const float* ow = (const float*)d_in[15];
    const float* ob = (const float*)d_in[16];

    float* ws = (float*)d_ws;
    const size_t SZ_HD = (size_t)CBN * CL * CHD;
    const size_t SZ_HDH = (size_t)CBN * CL * CHDH;
    float* qh   = ws;
    float* khb  = qh + SZ_HD;
    float* vhb  = khb + SZ_HD;
    float* gz2b = vhb + SZ_HD;
    float* z2sb = gz2b + SZ_HD;
    float* x2b  = z2sb + SZ_HD;
    float* gz1b = x2b + SZ_HDH;
    float* x2qb = gz1b + SZ_HDH;
    float* lrb  = x2qb + SZ_HDH;
    float* cumb = lrb + (size_t)CBN * CL;
    float* wdcb = cumb + (size_t)CBN * CL;
    unsigned short* xbf  = (unsigned short*)(wdcb + (size_t)CBN * CL);
    unsigned short* qwbf = xbf + (size_t)CB * CL * CD;
    unsigned short* kwbf = qwbf + (size_t)CD * CD;
    unsigned short* vwbf = kwbf + (size_t)CD * CD;
    unsigned short* owh  = vwbf + (size_t)CD * CD;
    unsigned short* owl  = owh + (size_t)CD * CD;

    unsigned short* qbf   = (unsigned short*)qh;
    unsigned short* kbf   = qbf + SZ_HD;
    unsigned short* ktbf  = (unsigned short*)khb;
    unsigned short* w1bf  = ktbf + SZ_HD;
    unsigned short* w2bf  = w1bf + (size_t)CBN * CHDH * CHD;
    unsigned short* w2tbf = w2bf + (size_t)CBN * CHDH * CHD;
    unsigned short* gz2t  = (unsigned short*)gz2b;
    unsigned short* x2t   = (unsigned short*)x2b;
    unsigned short* gz1t  = (unsigned short*)gz1b;
    unsigned short* x2q   = (unsigned short*)x2qb;
    unsigned short* x2bf  = x2q + SZ_HDH;
    float* w1part = qh;
    float* w2part = vhb;

    float* outp = (float*)d_out;
    float* w1n = outp + (size_t)CB * CL * CD;
    float* w2n = w1n + (size_t)CBN * CHDH * CHD;

    conv_kernel<<<6912, 256, 0, stream>>>(x, qw, kw, vw, W1, W2, ow, xbf, qwbf, kwbf,
                                          vwbf, w1bf, w2bf, w2tbf, owh, owl);
    qkv_mfma<<<dim3(24, 16), 512, 0, stream>>>(xbf, qwbf, qb, kb, vb, qbf, kbf, ktbf,
                                               vhb);
    lrwd_kernel<<<CB * CL, 64, 0, stream>>>(x, lblr, fclr_w, fclr_b, lbwd, fcwd_w,
                                            fcwd_b, lrb, cumb);
    scan_kernel<<<CBN, 64, 0, stream>>>(cumb, wdcb);
    mlp_mfma<<<dim3(CL / 64, CBN), 256, 0, stream>>>(kbf, vhb, w1bf, w2bf, w2tbf,
                                                     x2bf, x2t, gz1t, gz2t);
    attn1_mfma<<<dim3(8, CBN), 512, 0, stream>>>(qbf, kbf, gz1t, w1bf, lrb, cumb,
                                                 wdcb, x2q);
    w1n_part<<<dim3(8, CBN), 256, 0, stream>>>(gz1t, ktbf, lrb, cumb, w1part);
    w2n_part<<<dim3(8, CBN), 256, 0, stream>>>(gz2t, x2t, lrb, cumb, w2part);
    wn_red<<<512, 256, 0, stream>>>(w1part, w2part, W1, W2, cumb, w1n, w2n);
    attn2_mfma<<<dim3(8, CBN), 512, 0, stream>>>(x2q, x2bf, gz2t, w2bf, lrb, cumb,
                                                 wdcb, z2sb);
    gemm_obf<<<dim3(CD / 64, (CB * CL) / 64), 256, 0, stream>>>(z2sb, owh, owl, ob,
                                                                outp);
}

// Round 13
// 248.561 us; speedup vs baseline: 1.1430x; 1.0117x over previous
//
#include <hip/hip_runtime.h>

constexpr int CB = 2, CL = 1024, CD = 1024, CNH = 16, CHD = 64, CHDH = 128, CBN = CB * CNH;

__device__ __forceinline__ float sigf(float x) { return 1.0f / (1.0f + __expf(-x)); }

__device__ __forceinline__ unsigned short f2bf(float x) {
    unsigned u = __float_as_uint(x);
    u += 0x7fffu + ((u >> 16) & 1u);
    return (unsigned short)(u >> 16);
}
__device__ __forceinline__ unsigned pk2(float a, float b) {
    return (unsigned)f2bf(a) | ((unsigned)f2bf(b) << 16);
}
__device__ __forceinline__ unsigned pkus(unsigned short a, unsigned short b) {
    return (unsigned)a | ((unsigned)b << 16);
}
__device__ __forceinline__ float bf2f(unsigned short u) {
    return __uint_as_float(((unsigned)u) << 16);
}

typedef __attribute__((ext_vector_type(8))) short short8v;
typedef __attribute__((ext_vector_type(4))) float f32x4;
#define MFMA16(a, b, c) __builtin_amdgcn_mfma_f32_16x16x32_bf16(a, b, c, 0, 0, 0)

// ---------------------------------------------------------------------------
// Merged conversions.
// ---------------------------------------------------------------------------
__global__ __launch_bounds__(256) void conv_kernel(
    const float* __restrict__ x, const float* __restrict__ qw,
    const float* __restrict__ kw, const float* __restrict__ vw,
    const float* __restrict__ W1, const float* __restrict__ W2,
    const float* __restrict__ ow, unsigned short* __restrict__ xb,
    unsigned short* __restrict__ qwb, unsigned short* __restrict__ kwb,
    unsigned short* __restrict__ vwb, unsigned short* __restrict__ w1b,
    unsigned short* __restrict__ w2b, unsigned short* __restrict__ w2t,
    unsigned short* __restrict__ owh, unsigned short* __restrict__ owl) {
    int i = blockIdx.x * 256 + threadIdx.x;
    if (i < 1310720) {
        const float* s;
        unsigned short* d;
        int off;
        if (i < 524288) { s = x; d = xb; off = i; }
        else if (i < 786432) { s = qw; d = qwb; off = i - 524288; }
        else if (i < 1048576) { s = kw; d = kwb; off = i - 786432; }
        else { s = vw; d = vwb; off = i - 1048576; }
        float4 v = *(const float4*)(s + (size_t)off * 4);
        *(uint2*)(d + (size_t)off * 4) = make_uint2(pk2(v.x, v.y), pk2(v.z, v.w));
    } else if (i < 1507328) {
        int j = i - 1310720;
        if (j < 65536) {
            size_t e = (size_t)j * 4;
            float4 v = *(const float4*)(W1 + e);
            *(uint2*)(w1b + e) = make_uint2(pk2(v.x, v.y), pk2(v.z, v.w));
        } else if (j < 131072) {
            size_t e = (size_t)(j - 65536) * 4;
            float4 v = *(const float4*)(W2 + e);
            *(uint2*)(w2b + e) = make_uint2(pk2(v.x, v.y), pk2(v.z, v.w));
        } else {
            size_t e = (size_t)(j - 131072) * 4;
            int bn = (int)(e >> 13), rem = (int)(e & 8191);
            int h = rem >> 6, d0 = rem & 63;
            const float* src = W2 + (size_t)bn * CHD * CHDH;
            float a = src[(d0 + 0) * CHDH + h], b = src[(d0 + 1) * CHDH + h];
            float c = src[(d0 + 2) * CHDH + h], dd = src[(d0 + 3) * CHDH + h];
            *(uint2*)(w2t + e) = make_uint2(pk2(a, b), pk2(c, dd));
        }
    } else {
        size_t e = (size_t)(i - 1507328) * 4;
        float4 v = *(const float4*)(ow + e);
        unsigned short h0 = f2bf(v.x), h1 = f2bf(v.y), h2 = f2bf(v.z), h3 = f2bf(v.w);
        *(uint2*)(owh + e) = make_uint2(pkus(h0, h1), pkus(h2, h3));
        *(uint2*)(owl + e) = make_uint2(
            pk2(v.x - bf2f(h0), v.y - bf2f(h1)), pk2(v.z - bf2f(h2), v.w - bf2f(h3)));
    }
}

// ---------------------------------------------------------------------------
// Merged q/k/v projection GEMM: 128x128 tile, K=1024, 512 threads.
// ---------------------------------------------------------------------------
__global__ __launch_bounds__(512) void qkv_mfma(
    const unsigned short* __restrict__ xbf, const unsigned short* __restrict__ wqkv,
    const float* __restrict__ qb, const float* __restrict__ kb,
    const float* __restrict__ vb, unsigned short* __restrict__ qbf,
    unsigned short* __restrict__ kbf, unsigned short* __restrict__ ktbf,
    float* __restrict__ vhb) {
    __shared__ __align__(16) unsigned short SH[2][128][72];
    const int t = threadIdx.x;
    const int c0 = blockIdx.x << 7, r0 = blockIdx.y << 7;
    const int wvid = t >> 6, lane = t & 63;
    const int wm = wvid >> 2, wn = wvid & 3;
    const int lm = lane & 15, lg = lane >> 4;
    f32x4 acc[4][2];
#pragma unroll
    for (int i = 0; i < 4; ++i)
#pragma unroll
        for (int j = 0; j < 2; ++j) acc[i][j] = (f32x4){0.f, 0.f, 0.f, 0.f};
    for (int kc = 0; kc < CD; kc += 64) {
        for (int i = t; i < 1024; i += 512) {
            int r = i >> 3, c = (i & 7) * 8;
            *(uint4*)&SH[0][r][c] = *(const uint4*)(xbf + (size_t)(r0 + r) * CD + kc + c);
            *(uint4*)&SH[1][r][c] = *(const uint4*)(wqkv + (size_t)(c0 + r) * CD + kc + c);
        }
        __syncthreads();
#pragma unroll
        for (int m16 = 0; m16 < 4; ++m16)
#pragma unroll
            for (int n16 = 0; n16 < 2; ++n16)
#pragma unroll
                for (int ks = 0; ks < 2; ++ks) {
                    short8v a = *(const short8v*)&SH[0][wm * 64 + m16 * 16 + lm]
                                                   [ks * 32 + lg * 8];
                    short8v b = *(const short8v*)&SH[1][wn * 32 + n16 * 16 + lm]
                                                   [ks * 32 + lg * 8];
                    acc[m16][n16] = MFMA16(a, b, acc[m16][n16]);
                }
        __syncthreads();
    }
    const int which = c0 >> 10;
    const int ccb = c0 & 1023;
    const float* bias = which == 0 ? qb : (which == 1 ? kb : vb);
    const int b = r0 >> 10, lb0 = r0 & 1023;
    float(*Os)[132] = (float(*)[132])SH;
    for (int half = 0; half < 2; ++half) {
        if (wm == half) {
#pragma unroll
            for (int m16 = 0; m16 < 4; ++m16)
#pragma unroll
                for (int n16 = 0; n16 < 2; ++n16) {
                    int col = wn * 32 + n16 * 16 + lm;
                    float bb = bias[ccb + col];
#pragma unroll
                    for (int r = 0; r < 4; ++r)
                        Os[m16 * 16 + lg * 4 + r][col] = acc[m16][n16][r] + bb;
                }
        }
        __syncthreads();
        const int lbase = lb0 + half * 64;
        if (which == 2) {
            for (int i = t; i < 2048; i += 512) {
                int r = i >> 5, c = (i & 31) * 4;
                int n = (ccb + c) >> 6, d = (ccb + c) & 63;
                *(float4*)(vhb + (((size_t)b * CNH + n) * CL + lbase + r) * 64 + d) =
                    *(const float4*)&Os[r][c];
            }
        } else {
            unsigned short* dst = which == 0 ? qbf : kbf;
            for (int i = t; i < 2048; i += 512) {
                int r = i >> 5, c = (i & 31) * 4;
                int n = (ccb + c) >> 6, d = (ccb + c) & 63;
                float4 v4 = *(const float4*)&Os[r][c];
                *(uint2*)(dst + (((size_t)b * CNH + n) * CL + lbase + r) * 64 + d) =
                    make_uint2(pk2(v4.x, v4.y), pk2(v4.z, v4.w));
            }
            if (which == 1) {
                for (int i = t; i < 1024; i += 512) {
                    int col = i >> 3, lb = (i & 7) * 8;
                    int n = (ccb + col) >> 6, d = (ccb + col) & 63;
                    uint4 u;
                    u.x = pk2(Os[lb + 0][col], Os[lb + 1][col]);
                    u.y = pk2(Os[lb + 2][col], Os[lb + 3][col]);
                    u.z = pk2(Os[lb + 4][col], Os[lb + 5][col]);
                    u.w = pk2(Os[lb + 6][col], Os[lb + 7][col]);
                    *(uint4*)(ktbf + (((size_t)b * CNH + n) * 64 + d) * CL + lbase + lb) = u;
                }
            }
        }
        __syncthreads();
    }
}

// ---------------------------------------------------------------------------
// Split-precision MFMA o-projection.
// ---------------------------------------------------------------------------
__global__ __launch_bounds__(256) void gemm_obf(const float* __restrict__ A,
                                                const unsigned short* __restrict__ Bh,
                                                const unsigned short* __restrict__ Bl,
                                                const float* __restrict__ bias,
                                                float* __restrict__ C) {
    __shared__ __align__(16) unsigned short SM[4][64][72];
    const int t = threadIdx.x;
    const int r0 = blockIdx.y << 6, c0 = blockIdx.x << 6;
    const int wv = t >> 6, lane = t & 63;
    const int lm = lane & 15, lg = lane >> 4;
    const int b = r0 >> 10, lb0 = r0 & 1023;
    f32x4 acc[4];
#pragma unroll
    for (int i = 0; i < 4; ++i) acc[i] = (f32x4){0.f, 0.f, 0.f, 0.f};
    for (int kc = 0; kc < CD; kc += 64) {
        for (int i = t; i < 1024; i += 256) {
            int r = i >> 4, c4 = (i & 15) * 4;
            int ak = kc + c4, n = ak >> 6, d = ak & 63;
            float4 v = *(const float4*)(A + ((((size_t)b * CNH + n) * CL + lb0 + r) << 6) + d);
            unsigned short h0 = f2bf(v.x), h1 = f2bf(v.y), h2 = f2bf(v.z), h3 = f2bf(v.w);
            *(uint2*)&SM[0][r][c4] = make_uint2(pkus(h0, h1), pkus(h2, h3));
            *(uint2*)&SM[1][r][c4] = make_uint2(
                pk2(v.x - bf2f(h0), v.y - bf2f(h1)), pk2(v.z - bf2f(h2), v.w - bf2f(h3)));
        }
        for (int i = t; i < 512; i += 256) {
            int r = i >> 3, c = (i & 7) * 8;
            *(uint4*)&SM[2][r][c] = *(const uint4*)(Bh + (size_t)(c0 + r) * CD + kc + c);
            *(uint4*)&SM[3][r][c] = *(const uint4*)(Bl + (size_t)(c0 + r) * CD + kc + c);
        }
        __syncthreads();
#pragma unroll
        for (int n16 = 0; n16 < 4; ++n16)
#pragma unroll
            for (int ks = 0; ks < 2; ++ks) {
                short8v ah = *(const short8v*)&SM[0][wv * 16 + lm][ks * 32 + lg * 8];
                short8v al = *(const short8v*)&SM[1][wv * 16 + lm][ks * 32 + lg * 8];
                short8v bh = *(const short8v*)&SM[2][n16 * 16 + lm][ks * 32 + lg * 8];
                short8v bl = *(const short8v*)&SM[3][n16 * 16 + lm][ks * 32 + lg * 8];
                acc[n16] = MFMA16(ah, bh, acc[n16]);
                acc[n16] = MFMA16(ah, bl, acc[n16]);
                acc[n16] = MFMA16(al, bh, acc[n16]);
            }
        __syncthreads();
    }
    float(*Os)[68] = (float(*)[68])SM;
#pragma unroll
    for (int n16 = 0; n16 < 4; ++n16) {
        float bb = bias[c0 + n16 * 16 + lm];
#pragma unroll
        for (int r = 0; r < 4; ++r)
            Os[wv * 16 + lg * 4 + r][n16 * 16 + lm] = acc[n16][r] + bb;
    }
    __syncthreads();
    for (int i = t; i < 1024; i += 256) {
        int r = i >> 4, c = (i & 15) * 4;
        *(float4*)(C + (size_t)(r0 + r) * CD + c0 + c) = *(const float4*)&Os[r][c];
    }
}

// ---------------------------------------------------------------------------
// lr / log_wd projections.
// ---------------------------------------------------------------------------
__global__ __launch_bounds__(64) void lrwd_kernel(
    const float* __restrict__ x, const float* __restrict__ lblr,
    const float* __restrict__ fclr_w, const float* __restrict__ fclr_b,
    const float* __restrict__ lbwd, const float* __restrict__ fcwd_w,
    const float* __restrict__ fcwd_b, float* __restrict__ lrp,
    float* __restrict__ logwd) {
    const int r = blockIdx.x;
    const int b = r >> 10, l = r & 1023;
    const int lane = threadIdx.x;
    float xv[16];
#pragma unroll
    for (int j = 0; j < 16; ++j) xv[j] = x[(size_t)r * CD + lane + 64 * j];
    for (int n = 0; n < CNH; ++n) {
        float d1 = 0.f, d2 = 0.f;
#pragma unroll
        for (int j = 0; j < 16; ++j) {
            d1 += xv[j] * fclr_w[(size_t)n * CD + lane + 64 * j];
            d2 += xv[j] * fcwd_w[(size_t)n * CD + lane + 64 * j];
        }
#pragma unroll
        for (int s = 32; s > 0; s >>= 1) {
            d1 += __shfl_down(d1, s);
            d2 += __shfl_down(d2, s);
        }
        if (lane == 0) {
            lrp[((size_t)b * CNH + n) * CL + l] = __expf(lblr[n]) * sigf(d1 + fclr_b[n]);
            logwd[((size_t)b * CNH + n) * CL + l] =
                log1pf(-__expf(lbwd[n]) * sigf(d2 + fcwd_b[n]));
        }
    }
}

// ---------------------------------------------------------------------------
// Inclusive prefix sum of log_wd -> cum, plus wdc = exp(cum).
// ---------------------------------------------------------------------------
__global__ __launch_bounds__(64) void scan_kernel(float* __restrict__ cum,
                                                  float* __restrict__ wdc) {
    const int bn = blockIdx.x;
    const int lane = threadIdx.x;
    float* p = cum + (size_t)bn * CL;
    float v[16];
#pragma unroll
    for (int j = 0; j < 16; ++j) v[j] = p[lane * 16 + j];
#pragma unroll
    for (int j = 1; j < 16; ++j) v[j] += v[j - 1];
    float tot = v[15];
    float inc = tot;
#pragma unroll
    for (int s = 1; s < 64; s <<= 1) {
        float tv = __shfl_up(inc, s);
        if (lane >= s) inc += tv;
    }
    const float pre = inc - tot;
#pragma unroll
    for (int j = 0; j < 16; ++j) {
        float c = pre + v[j];
        p[lane * 16 + j] = c;
        wdc[(size_t)bn * CL + lane * 16 + j] = __expf(c);
    }
}

// ---------------------------------------------------------------------------
// MFMA MLP fwd/bwd over 64 tokens.
// ---------------------------------------------------------------------------
__global__ __launch_bounds__(256) void mlp_mfma(
    const unsigned short* __restrict__ kbf, const float* __restrict__ vh,
    const unsigned short* __restrict__ w1bf, const unsigned short* __restrict__ w2bf,
    const unsigned short* __restrict__ w2tbf, unsigned short* __restrict__ x2bf,
    unsigned short* __restrict__ x2t, unsigned short* __restrict__ gz1t,
    unsigned short* __restrict__ gz2t) {
    __shared__ __align__(16) unsigned short RA[128][72];
    __shared__ __align__(16) unsigned short RB[64][72];
    __shared__ __align__(16) unsigned short RC[64][136];
    __shared__ __align__(16) unsigned short X2s[64][136];
    const int bn = blockIdx.y, l0 = blockIdx.x << 6;
    const int t = threadIdx.x;
    const int wv = t >> 6, lane = t & 63;
    const int lm = lane & 15, lg = lane >> 4;
    {
        const unsigned short* kg = kbf + ((size_t)bn * CL + l0) * CHD;
        for (int i = t; i < 512; i += 256) {
            int r = i >> 3, c = (i & 7) * 8;
            *(uint4*)&RB[r][c] = *(const uint4*)(kg + (size_t)r * CHD + c);
        }
        const unsigned short* w1g = w1bf + (size_t)bn * CHDH * CHD;
        for (int i = t; i < 1024; i += 256) {
            int r = i >> 3, c = (i & 7) * 8;
            *(uint4*)&RA[r][c] = *(const uint4*)(w1g + (size_t)r * CHD + c);
        }
        const unsigned short* w2g = w2bf + (size_t)bn * CHD * CHDH;
        for (int i = t; i < 1024; i += 256) {
            int r = i >> 4, c = (i & 15) * 8;
            *(uint4*)&RC[r][c] = *(const uint4*)(w2g + (size_t)r * CHDH + c);
        }
    }
    __syncthreads();
    f32x4 acc1[4][2];
#pragma unroll
    for (int i = 0; i < 4; ++i)
#pragma unroll
        for (int j = 0; j < 2; ++j) acc1[i][j] = (f32x4){0.f, 0.f, 0.f, 0.f};
#pragma unroll
    for (int m16 = 0; m16 < 4; ++m16)
#pragma unroll
        for (int hh = 0; hh < 2; ++hh) {
            int h16 = wv * 2 + hh;
#pragma unroll
            for (int ks = 0; ks < 2; ++ks) {
                short8v a = *(const short8v*)&RB[m16 * 16 + lm][ks * 32 + lg * 8];
                short8v b = *(const short8v*)&RA[h16 * 16 + lm][ks * 32 + lg * 8];
                acc1[m16][hh] = MFMA16(a, b, acc1[m16][hh]);
            }
        }
#pragma unroll
    for (int m16 = 0; m16 < 4; ++m16)
#pragma unroll
        for (int hh = 0; hh < 2; ++hh)
#pragma unroll
            for (int r = 0; r < 4; ++r) {
                float a = acc1[m16][hh][r];
                X2s[m16 * 16 + lg * 4 + r][(wv * 2 + hh) * 16 + lm] = f2bf(a * sigf(a));
            }
    __syncthreads();
    {
        const unsigned short* w2tg = w2tbf + (size_t)bn * CHDH * CHD;
        for (int i = t; i < 1024; i += 256) {
            int r = i >> 3, c = (i & 7) * 8;
            *(uint4*)&RA[r][c] = *(const uint4*)(w2tg + (size_t)r * CHD + c);
        }
    }
    {
        f32x4 acc2[4];
#pragma unroll
        for (int i = 0; i < 4; ++i) acc2[i] = (f32x4){0.f, 0.f, 0.f, 0.f};
#pragma unroll
        for (int m16 = 0; m16 < 4; ++m16)
#pragma unroll
            for (int ks = 0; ks < 4; ++ks) {
                short8v a = *(const short8v*)&X2s[m16 * 16 + lm][ks * 32 + lg * 8];
                short8v b = *(const short8v*)&RC[wv * 16 + lm][ks * 32 + lg * 8];
                acc2[m16] = MFMA16(a, b, acc2[m16]);
            }
#pragma unroll
        for (int m16 = 0; m16 < 4; ++m16)
#pragma unroll
            for (int r = 0; r < 4; ++r) {
                int l = l0 + m16 * 16 + lg * 4 + r;
                float v = vh[((size_t)bn * CL + l) * 64 + wv * 16 + lm];
                RB[m16 * 16 + lg * 4 + r][wv * 16 + lm] = f2bf(acc2[m16][r] - v);
            }
    }
    __syncthreads();
#pragma unroll
    for (int m16 = 0; m16 < 4; ++m16)
#pragma unroll
        for (int hh = 0; hh < 2; ++hh) {
            int h16 = wv * 2 + hh;
            f32x4 p = (f32x4){0.f, 0.f, 0.f, 0.f};
#pragma unroll
            for (int ks = 0; ks < 2; ++ks) {
                short8v a = *(const short8v*)&RB[m16 * 16 + lm][ks * 32 + lg * 8];
                short8v b = *(const short8v*)&RA[h16 * 16 + lm][ks * 32 + lg * 8];
                p = MFMA16(a, b, p);
            }
#pragma unroll
            for (int r = 0; r < 4; ++r) {
                float zz = acc1[m16][hh][r];
                float s = sigf(zz);
                float sil = zz * s;
                RC[m16 * 16 + lg * 4 + r][h16 * 16 + lm] =
                    f2bf((sil + s * (1.f - sil)) * p[r]);
            }
        }
    __syncthreads();
    for (int i = t; i < 1024; i += 256) {
        int r = i >> 4, c = (i & 15) * 8;
        *(uint4*)(x2bf + ((size_t)bn * CL + l0 + r) * CHDH + c) = *(const uint4*)&X2s[r][c];
    }
    for (int i = t; i < 1024; i += 256) {
        int h = i >> 3, lb = (i & 7) * 8;
        uint4 u;
        u.x = pkus(X2s[lb + 0][h], X2s[lb + 1][h]);
        u.y = pkus(X2s[lb + 2][h], X2s[lb + 3][h]);
        u.z = pkus(X2s[lb + 4][h], X2s[lb + 5][h]);
        u.w = pkus(X2s[lb + 6][h], X2s[lb + 7][h]);
        *(uint4*)(x2t + ((size_t)bn * CHDH + h) * CL + l0 + lb) = u;
    }
    for (int i = t; i < 1024; i += 256) {
        int h = i >> 3, lb = (i & 7) * 8;
        uint4 u;
        u.x = pkus(RC[lb + 0][h], RC[lb + 1][h]);
        u.y = pkus(RC[lb + 2][h], RC[lb + 3][h]);
        u.z = pkus(RC[lb + 4][h], RC[lb + 5][h]);
        u.w = pkus(RC[lb + 6][h], RC[lb + 7][h]);
        *(uint4*)(gz1t + ((size_t)bn * CHDH + h) * CL + l0 + lb) = u;
    }
    for (int i = t; i < 512; i += 256) {
        int d = i >> 3, lb = (i & 7) * 8;
        uint4 u;
        u.x = pkus(RB[lb + 0][d], RB[lb + 1][d]);
        u.y = pkus(RB[lb + 2][d], RB[lb + 3][d]);
        u.z = pkus(RB[lb + 4][d], RB[lb + 5][d]);
        u.w = pkus(RB[lb + 6][d], RB[lb + 7][d]);
        *(uint4*)(gz2t + ((size_t)bn * CHD + d) * CL + l0 + lb) = u;
    }
}

// ---------------------------------------------------------------------------
// attn1: balanced dual-issue schedule, 9 iterations for every block.
//   phase1 (i<=p): both groups process shared tile i vs own m-tile.
//   phase2 (i>p):  both groups target m-tile B; A takes tiles p+1,p+3,...
//                  B takes p+2,p+4,...; A's partial added to B at end.
// ---------------------------------------------------------------------------
__global__ __launch_bounds__(512) void attn1_mfma(
    const unsigned short* __restrict__ qbf, const unsigned short* __restrict__ kbf,
    const unsigned short* __restrict__ gz1t, const unsigned short* __restrict__ w1bf,
    const float* __restrict__ lrp, const float* __restrict__ cump,
    const float* __restrict__ wdcp, unsigned short* __restrict__ x2q) {
    __shared__ __align__(16) unsigned short SH[46080];
    __shared__ float lrl[2][64], cuml[2][64], cumm[128], wdcm[128];
    unsigned short(*Qb)[72] = (unsigned short(*)[72])SH;            // [128][72]
    unsigned short(*Kb)[72] = (unsigned short(*)[72])(SH + 9216);   // [2*64][72]
    unsigned short(*GT)[72] = (unsigned short(*)[72])(SH + 18432);  // [2*128][72]
    unsigned short(*Pm)[72] = (unsigned short(*)[72])(SH + 36864);  // [128][72]
    const int bx = blockIdx.x, by = blockIdx.y;
    const int bn = (bx << 2) + (by >> 3);  // XCD swizzle
    const int p = by & 7;
    const int mtB = 15 - p;
    const int m0A = p << 6, m0B = mtB << 6;
    const int t = threadIdx.x;
    const int wv = t >> 6, lane = t & 63;
    const int grp = wv >> 2, w4 = wv & 3;
    const int lm = lane & 15, lg = lane >> 4;
    const int qbase = grp << 6;
    const int sr = t >> 3, sc = (t & 7) * 8;
    uint4 pk[2], pg[2][2];
    float plr[2], pcu[2];
    {  // prefetch tile 0 into slot 0
        const unsigned short* kg = kbf + (size_t)bn * CL * CHD;
        pk[0] = *(const uint4*)(kg + (size_t)sr * CHD + sc);
        const unsigned short* gg = gz1t + (size_t)bn * CHDH * CL;
        pg[0][0] = *(const uint4*)(gg + (size_t)sr * CL + sc);
        pg[0][1] = *(const uint4*)(gg + (size_t)(sr + 64) * CL + sc);
        if (t < 64) {
            plr[0] = lrp[(size_t)bn * CL + t];
            pcu[0] = cump[(size_t)bn * CL + t];
        }
    }
    {  // stage Q (both tiles) + W1 into GT rows 0..127
        const unsigned short* qgA = qbf + ((size_t)bn * CL + m0A) * CHD;
        const unsigned short* qgB = qbf + ((size_t)bn * CL + m0B) * CHD;
        *(uint4*)&Qb[sr][sc] = *(const uint4*)(qgA + (size_t)sr * CHD + sc);
        *(uint4*)&Qb[64 + sr][sc] = *(const uint4*)(qgB + (size_t)sr * CHD + sc);
        const unsigned short* wg = w1bf + (size_t)bn * CHDH * CHD;
        *(uint4*)&GT[sr][sc] = *(const uint4*)(wg + (size_t)sr * CHD + sc);
        *(uint4*)&GT[64 + sr][sc] = *(const uint4*)(wg + (size_t)(sr + 64) * CHD + sc);
        if (t < 128) {
            int mm = (t < 64) ? (m0A + t) : (m0B + t - 64);
            cumm[t] = cump[(size_t)bn * CL + mm];
            wdcm[t] = wdcp[(size_t)bn * CL + mm];
        }
    }
    __syncthreads();
    f32x4 accO[4][2], accP[4][2];
#pragma unroll
    for (int i = 0; i < 4; ++i)
#pragma unroll
        for (int j = 0; j < 2; ++j) {
            accO[i][j] = (f32x4){0.f, 0.f, 0.f, 0.f};
            accP[i][j] = (f32x4){0.f, 0.f, 0.f, 0.f};
        }
    {  // init: own m-tile x W1 (GT rows 0..127)
        short8v wf[2][2];
#pragma unroll
        for (int hh = 0; hh < 2; ++hh)
#pragma unroll
            for (int ks = 0; ks < 2; ++ks)
                wf[hh][ks] =
                    *(const short8v*)&GT[(w4 * 2 + hh) * 16 + lm][ks * 32 + lg * 8];
#pragma unroll
        for (int m16 = 0; m16 < 4; ++m16) {
            short8v qa[2];
#pragma unroll
            for (int ks = 0; ks < 2; ++ks)
                qa[ks] = *(const short8v*)&Qb[qbase + m16 * 16 + lm][ks * 32 + lg * 8];
#pragma unroll
            for (int hh = 0; hh < 2; ++hh)
#pragma unroll
                for (int ks = 0; ks < 2; ++ks)
                    accO[m16][hh] = MFMA16(qa[ks], wf[hh][ks], accO[m16][hh]);
        }
    }
#pragma unroll
    for (int m16 = 0; m16 < 4; ++m16)
#pragma unroll
        for (int r = 0; r < 4; ++r) {
            float w = wdcm[qbase + m16 * 16 + lg * 4 + r];
            accO[m16][0][r] *= w;
            accO[m16][1][r] *= w;
        }
    __syncthreads();  // W1 reads done before buffer-0 publish
    for (int i = 0; i < 9; ++i) {
        const bool sh = (i <= p);
        const int tA = sh ? i : (p + 1 + ((i - p - 1) << 1));
        const int tB = sh ? i : tA + 1;
        const bool hasB = sh || (tB <= mtB);
        // publish prefetched tiles
        *(uint4*)&Kb[sr][sc] = pk[0];
        *(uint4*)&GT[sr][sc] = pg[0][0];
        *(uint4*)&GT[64 + sr][sc] = pg[0][1];
        if (t < 64) { lrl[0][t] = plr[0]; cuml[0][t] = pcu[0]; }
        if (!sh && hasB) {
            *(uint4*)&Kb[64 + sr][sc] = pk[1];
            *(uint4*)&GT[128 + sr][sc] = pg[1][0];
            *(uint4*)&GT[192 + sr][sc] = pg[1][1];
            if (t < 64) { lrl[1][t] = plr[1]; cuml[1][t] = pcu[1]; }
        }
        __syncthreads();
        // prefetch iteration i+1
        if (i + 1 < 9) {
            const bool sh2 = (i + 1 <= p);
            const int tA2 = sh2 ? (i + 1) : (p + 1 + ((i - p) << 1));
            const int tB2 = tA2 + 1;
            {
                const int ln = tA2 << 6;
                const unsigned short* kg = kbf + ((size_t)bn * CL + ln) * CHD;
                pk[0] = *(const uint4*)(kg + (size_t)sr * CHD + sc);
                const unsigned short* gg = gz1t + (size_t)bn * CHDH * CL + ln;
                pg[0][0] = *(const uint4*)(gg + (size_t)sr * CL + sc);
                pg[0][1] = *(const uint4*)(gg + (size_t)(sr + 64) * CL + sc);
                if (t < 64) {
                    plr[0] = lrp[(size_t)bn * CL + ln + t];
                    pcu[0] = cump[(size_t)bn * CL + ln + t];
                }
            }
            if (!sh2 && tB2 <= mtB) {
                const int ln = tB2 << 6;
                const unsigned short* kg = kbf + ((size_t)bn * CL + ln) * CHD;
                pk[1] = *(const uint4*)(kg + (size_t)sr * CHD + sc);
                const unsigned short* gg = gz1t + (size_t)bn * CHDH * CL + ln;
                pg[1][0] = *(const uint4*)(gg + (size_t)sr * CL + sc);
                pg[1][1] = *(const uint4*)(gg + (size_t)(sr + 64) * CL + sc);
                if (t < 64) {
                    plr[1] = lrp[(size_t)bn * CL + ln + t];
                    pcu[1] = cump[(size_t)bn * CL + ln + t];
                }
            }
        }
        // scores
        const int myt = grp ? tB : tA;
        const int mybuf = (sh || grp == 0) ? 0 : 1;
        const bool act = grp ? hasB : true;
        const int qrow = sh ? qbase : 64;
        const int m0eff = sh ? (grp ? m0B : m0A) : m0B;
        const int cmb = sh ? qbase : 64;
        if (act) {
            const int l0 = myt << 6;
            short8v kf[2];
#pragma unroll
            for (int ks = 0; ks < 2; ++ks)
                kf[ks] = *(const short8v*)&Kb[mybuf * 64 + w4 * 16 + lm][ks * 32 + lg * 8];
#pragma unroll
            for (int m16 = 0; m16 < 4; ++m16) {
                f32x4 s = (f32x4){0.f, 0.f, 0.f, 0.f};
#pragma unroll
                for (int ks = 0; ks < 2; ++ks) {
                    short8v q = *(const short8v*)&Qb[qrow + m16 * 16 + lm][ks * 32 + lg * 8];
                    s = MFMA16(kf[ks], q, s);
                }
                int mloc = m16 * 16 + lm;
                int mabs = m0eff + mloc;
                float cm = cumm[cmb + mloc];
                unsigned short pv[4];
#pragma unroll
                for (int r = 0; r < 4; ++r) {
                    int lloc = w4 * 16 + lg * 4 + r;
                    float val = (mabs >= l0 + lloc)
                                    ? s[r] * lrl[mybuf][lloc] * __expf(cm - cuml[mybuf][lloc])
                                    : 0.f;
                    pv[r] = f2bf(val);
                }
                *(uint2*)&Pm[qbase + mloc][w4 * 16 + lg * 4] =
                    make_uint2(pkus(pv[0], pv[1]), pkus(pv[2], pv[3]));
            }
        }
        __syncthreads();
        // apply
        if (act) {
            short8v gt[2][2], pm[4][2];
#pragma unroll
            for (int hh = 0; hh < 2; ++hh)
#pragma unroll
                for (int ks = 0; ks < 2; ++ks)
                    gt[hh][ks] = *(const short8v*)&GT[mybuf * 128 + (w4 * 2 + hh) * 16 + lm]
                                                    [ks * 32 + lg * 8];
#pragma unroll
            for (int m16 = 0; m16 < 4; ++m16)
#pragma unroll
                for (int ks = 0; ks < 2; ++ks)
                    pm[m16][ks] = *(const short8v*)&Pm[qbase + m16 * 16 + lm]
                                                     [ks * 32 + lg * 8];
            if (sh || grp == 1) {
#pragma unroll
                for (int m16 = 0; m16 < 4; ++m16)
#pragma unroll
                    for (int hh = 0; hh < 2; ++hh) {
                        f32x4 pf = (f32x4){0.f, 0.f, 0.f, 0.f};
#pragma unroll
                        for (int ks = 0; ks < 2; ++ks)
                            pf = MFMA16(pm[m16][ks], gt[hh][ks], pf);
#pragma unroll
                        for (int r = 0; r < 4; ++r) accO[m16][hh][r] -= pf[r];
                    }
            } else {
#pragma unroll
                for (int m16 = 0; m16 < 4; ++m16)
#pragma unroll
                    for (int hh = 0; hh < 2; ++hh) {
                        f32x4 pf = (f32x4){0.f, 0.f, 0.f, 0.f};
#pragma unroll
                        for (int ks = 0; ks < 2; ++ks)
                            pf = MFMA16(pm[m16][ks], gt[hh][ks], pf);
#pragma unroll
                        for (int r = 0; r < 4; ++r) accP[m16][hh][r] -= pf[r];
                    }
            }
        }
        __syncthreads();
    }
    {  // cross-group reduction: A's accP -> B's accO
        float(*FS)[132] = (float(*)[132])SH;  // 64x132 f32 over Qb+Kb region
        if (grp == 0) {
#pragma unroll
            for (int m16 = 0; m16 < 4; ++m16)
#pragma unroll
                for (int hh = 0; hh < 2; ++hh)
#pragma unroll
                    for (int r = 0; r < 4; ++r)
                        FS[m16 * 16 + lg * 4 + r][(w4 * 2 + hh) * 16 + lm] =
                            accP[m16][hh][r];
        }
        __syncthreads();
        if (grp == 1) {
#pragma unroll
            for (int m16 = 0; m16 < 4; ++m16)
#pragma unroll
                for (int hh = 0; hh < 2; ++hh)
#pragma unroll
                    for (int r = 0; r < 4; ++r)
                        accO[m16][hh][r] +=
                            FS[m16 * 16 + lg * 4 + r][(w4 * 2 + hh) * 16 + lm];
        }
        __syncthreads();
    }
    {  // silu + store; Ob overlays GT+Pm region
        unsigned short(*Ob)[136] = (unsigned short(*)[136])(SH + 18432);
#pragma unroll
        for (int m16 = 0; m16 < 4; ++m16)
#pragma unroll
            for (int hh = 0; hh < 2; ++hh) {
                int h = (w4 * 2 + hh) * 16 + lm;
#pragma unroll
                for (int r = 0; r < 4; ++r) {
                    int mloc = m16 * 16 + lg * 4 + r;
                    float a = accO[m16][hh][r];
                    Ob[qbase + mloc][h] = f2bf(a * sigf(a));
                }
            }
        __syncthreads();
        unsigned short* og = x2q + (size_t)bn * CL * CHDH;
        for (int i = t; i < 2048; i += 512) {
            int r = i >> 4, c = (i & 15) * 8;
            int gm = (r < 64) ? (m0A + r) : (m0B + r - 64);
            *(uint4*)(og + (size_t)gm * CHDH + c) = *(const uint4*)&Ob[r][c];
        }
    }
}

// ---------------------------------------------------------------------------
// attn2: balanced dual-issue schedule (same as attn1).
// ---------------------------------------------------------------------------
__global__ __launch_bounds__(512) void attn2_mfma(
    const unsigned short* __restrict__ x2q, const unsigned short* __restrict__ x2bf,
    const unsigned short* __restrict__ gz2t, const unsigned short* __restrict__ w2bf,
    const float* __restrict__ lrp, const float* __restrict__ cump,
    const float* __restrict__ wdcp, float* __restrict__ z2s) {
    __shared__ __align__(16) unsigned short SH[53248];
    __shared__ float lrl[2][64], cuml[2][64], cumm[128], wdcm[128];
    unsigned short(*X2qb)[136] = (unsigned short(*)[136])SH;           // [128][136]
    unsigned short(*X2l)[136] = (unsigned short(*)[136])(SH + 17408);  // [2*64][136]
    unsigned short(*GT2)[72] = (unsigned short(*)[72])(SH + 34816);    // [2*64][72]
    unsigned short(*Pm)[72] = (unsigned short(*)[72])(SH + 44032);     // [128][72]
    const int bx = blockIdx.x, by = blockIdx.y;
    const int bn = (bx << 2) + (by >> 3);  // XCD swizzle
    const int p = by & 7;
    const int mtB = 15 - p;
    const int m0A = p << 6, m0B = mtB << 6;
    const int t = threadIdx.x;
    const int wv = t >> 6, lane = t & 63;
    const int grp = wv >> 2, w4 = wv & 3;
    const int lm = lane & 15, lg = lane >> 4;
    const int qbase = grp << 6;
    const int xr = t >> 4, xc = (t & 15) * 8;
    const int gr = t >> 3, gc = (t & 7) * 8;
    uint4 px[2][2], pgv[2];
    float plr[2], pcu[2];
    {  // prefetch tile 0 slot 0
        const unsigned short* kg = x2bf + (size_t)bn * CL * CHDH;
        px[0][0] = *(const uint4*)(kg + (size_t)xr * CHDH + xc);
        px[0][1] = *(const uint4*)(kg + (size_t)(xr + 32) * CHDH + xc);
        const unsigned short* gg = gz2t + (size_t)bn * CHD * CL;
        pgv[0] = *(const uint4*)(gg + (size_t)gr * CL + gc);
        if (t < 64) {
            plr[0] = lrp[(size_t)bn * CL + t];
            pcu[0] = cump[(size_t)bn * CL + t];
        }
    }
    {  // stage x2q (both) + W2 into X2l buffer 1
        const unsigned short* qgA = x2q + ((size_t)bn * CL + m0A) * CHDH;
        const unsigned short* qgB = x2q + ((size_t)bn * CL + m0B) * CHDH;
        *(uint4*)&X2qb[xr][xc] = *(const uint4*)(qgA + (size_t)xr * CHDH + xc);
        *(uint4*)&X2qb[xr + 32][xc] = *(const uint4*)(qgA + (size_t)(xr + 32) * CHDH + xc);
        *(uint4*)&X2qb[xr + 64][xc] = *(const uint4*)(qgB + (size_t)xr * CHDH + xc);
        *(uint4*)&X2qb[xr + 96][xc] = *(const uint4*)(qgB + (size_t)(xr + 32) * CHDH + xc);
        const unsigned short* wg = w2bf + (size_t)bn * CHD * CHDH;
        *(uint4*)&X2l[64 + xr][xc] = *(const uint4*)(wg + (size_t)xr * CHDH + xc);
        *(uint4*)&X2l[96 + xr][xc] = *(const uint4*)(wg + (size_t)(xr + 32) * CHDH + xc);
        if (t < 128) {
            int mm = (t < 64) ? (m0A + t) : (m0B + t - 64);
            cumm[t] = cump[(size_t)bn * CL + mm];
            wdcm[t] = wdcp[(size_t)bn * CL + mm];
        }
    }
    __syncthreads();
    f32x4 accO[4], accP[4];
#pragma unroll
    for (int i = 0; i < 4; ++i) {
        accO[i] = (f32x4){0.f, 0.f, 0.f, 0.f};
        accP[i] = (f32x4){0.f, 0.f, 0.f, 0.f};
    }
    {  // init: own m-tile x W2 (X2l buffer 1)
        short8v wf[4];
#pragma unroll
        for (int ks = 0; ks < 4; ++ks)
            wf[ks] = *(const short8v*)&X2l[64 + w4 * 16 + lm][ks * 32 + lg * 8];
#pragma unroll
        for (int m16 = 0; m16 < 4; ++m16)
#pragma unroll
            for (int ks = 0; ks < 4; ++ks) {
                short8v q =
                    *(const short8v*)&X2qb[qbase + m16 * 16 + lm][ks * 32 + lg * 8];
                accO[m16] = MFMA16(q, wf[ks], accO[m16]);
            }
    }
#pragma unroll
    for (int m16 = 0; m16 < 4; ++m16)
#pragma unroll
        for (int r = 0; r < 4; ++r) accO[m16][r] *= wdcm[qbase + m16 * 16 + lg * 4 + r];
    __syncthreads();  // W2 reads done (buffer 1 first overwritten at i=p+1)
    for (int i = 0; i < 9; ++i) {
        const bool sh = (i <= p);
        const int tA = sh ? i : (p + 1 + ((i - p - 1) << 1));
        const int tB = sh ? i : tA + 1;
        const bool hasB = sh || (tB <= mtB);
        *(uint4*)&X2l[xr][xc] = px[0][0];
        *(uint4*)&X2l[32 + xr][xc] = px[0][1];
        *(uint4*)&GT2[gr][gc] = pgv[0];
        if (t < 64) { lrl[0][t] = plr[0]; cuml[0][t] = pcu[0]; }
        if (!sh && hasB) {
            *(uint4*)&X2l[64 + xr][xc] = px[1][0];
            *(uint4*)&X2l[96 + xr][xc] = px[1][1];
            *(uint4*)&GT2[64 + gr][gc] = pgv[1];
            if (t < 64) { lrl[1][t] = plr[1]; cuml[1][t] = pcu[1]; }
        }
        __syncthreads();
        if (i + 1 < 9) {
            const bool sh2 = (i + 1 <= p);
            const int tA2 = sh2 ? (i + 1) : (p + 1 + ((i - p) << 1));
            const int tB2 = tA2 + 1;
            {
                const int ln = tA2 << 6;
                const unsigned short* kg = x2bf + ((size_t)bn * CL + ln) * CHDH;
                px[0][0] = *(const uint4*)(kg + (size_t)xr * CHDH + xc);
                px[0][1] = *(const uint4*)(kg + (size_t)(xr + 32) * CHDH + xc);
                const unsigned short* gg = gz2t + (size_t)bn * CHD * CL + ln;
                pgv[0] = *(const uint4*)(gg + (size_t)gr * CL + gc);
                if (t < 64) {
                    plr[0] = lrp[(size_t)bn * CL + ln + t];
                    pcu[0] = cump[(size_t)bn * CL + ln + t];
                }
            }
            if (!sh2 && tB2 <= mtB) {
                const int ln = tB2 << 6;
                const unsigned short* kg = x2bf + ((size_t)bn * CL + ln) * CHDH;
                px[1][0] = *(const uint4*)(kg + (size_t)xr * CHDH + xc);
                px[1][1] = *(const uint4*)(kg + (size_t)(xr + 32) * CHDH + xc);
                const unsigned short* gg = gz2t + (size_t)bn * CHD * CL + ln;
                pgv[1] = *(const uint4*)(gg + (size_t)gr * CL + gc);
                if (t < 64) {
                    plr[1] = lrp[(size_t)bn * CL + ln + t];
                    pcu[1] = cump[(size_t)bn * CL + ln + t];
                }
            }
        }
        const int myt = grp ? tB : tA;
        const int mybuf = (sh || grp == 0) ? 0 : 1;
        const bool act = grp ? hasB : true;
        const int qrow = sh ? qbase : 64;
        const int m0eff = sh ? (grp ? m0B : m0A) : m0B;
        const int cmb = sh ? qbase : 64;
        if (act) {
            const int l0 = myt << 6;
            short8v kf[4];
#pragma unroll
            for (int ks = 0; ks < 4; ++ks)
                kf[ks] =
                    *(const short8v*)&X2l[mybuf * 64 + w4 * 16 + lm][ks * 32 + lg * 8];
#pragma unroll
            for (int m16 = 0; m16 < 4; ++m16) {
                f32x4 s = (f32x4){0.f, 0.f, 0.f, 0.f};
#pragma unroll
                for (int ks = 0; ks < 4; ++ks) {
                    short8v q =
                        *(const short8v*)&X2qb[qrow + m16 * 16 + lm][ks * 32 + lg * 8];
                    s = MFMA16(kf[ks], q, s);
                }
                int mloc = m16 * 16 + lm;
                int mabs = m0eff + mloc;
                float cm = cumm[cmb + mloc];
                unsigned short pv[4];
#pragma unroll
                for (int r = 0; r < 4; ++r) {
                    int lloc = w4 * 16 + lg * 4 + r;
                    float val = (mabs >= l0 + lloc)
                                    ? s[r] * lrl[mybuf][lloc] * __expf(cm - cuml[mybuf][lloc])
                                    : 0.f;
                    pv[r] = f2bf(val);
                }
                *(uint2*)&Pm[qbase + mloc][w4 * 16 + lg * 4] =
                    make_uint2(pkus(pv[0], pv[1]), pkus(pv[2], pv[3]));
            }
        }
        __syncthreads();
        if (act) {
            short8v gt[2], pm[4][2];
#pragma unroll
            for (int ks = 0; ks < 2; ++ks)
                gt[ks] = *(const short8v*)&GT2[mybuf * 64 + w4 * 16 + lm][ks * 32 + lg * 8];
#pragma unroll
            for (int m16 = 0; m16 < 4; ++m16)
#pragma unroll
                for (int ks = 0; ks < 2; ++ks)
                    pm[m16][ks] = *(const short8v*)&Pm[qbase + m16 * 16 + lm]
                                                     [ks * 32 + lg * 8];
            if (sh || grp == 1) {
#pragma unroll
                for (int m16 = 0; m16 < 4; ++m16) {
                    f32x4 pf = (f32x4){0.f, 0.f, 0.f, 0.f};
#pragma unroll
                    for (int ks = 0; ks < 2; ++ks) pf = MFMA16(pm[m16][ks], gt[ks], pf);
#pragma unroll
                    for (int r = 0; r < 4; ++r) accO[m16][r] -= pf[r];
                }
            } else {
#pragma unroll
                for (int m16 = 0; m16 < 4; ++m16) {
                    f32x4 pf = (f32x4){0.f, 0.f, 0.f, 0.f};
#pragma unroll
                    for (int ks = 0; ks < 2; ++ks) pf = MFMA16(pm[m16][ks], gt[ks], pf);
#pragma unroll
                    for (int r = 0; r < 4; ++r) accP[m16][r] -= pf[r];
                }
            }
        }
        __syncthreads();
    }
    {  // cross-group reduction
        float(*FS)[68] = (float(*)[68])SH;  // 64x68 f32 over X2qb region
        if (grp == 0) {
#pragma unroll
            for (int m16 = 0; m16 < 4; ++m16)
#pragma unroll
                for (int r = 0; r < 4; ++r)
                    FS[m16 * 16 + lg * 4 + r][w4 * 16 + lm] = accP[m16][r];
        }
        __syncthreads();
        if (grp == 1) {
#pragma unroll
            for (int m16 = 0; m16 < 4; ++m16)
#pragma unroll
                for (int r = 0; r < 4; ++r)
                    accO[m16][r] += FS[m16 * 16 + lg * 4 + r][w4 * 16 + lm];
        }
        __syncthreads();
    }
    {  // store fp32 via LDS
        float(*Os)[68] = (float(*)[68])SH;
#pragma unroll
        for (int m16 = 0; m16 < 4; ++m16)
#pragma unroll
            for (int r = 0; r < 4; ++r)
                Os[qbase + m16 * 16 + lg * 4 + r][w4 * 16 + lm] = accO[m16][r];
        __syncthreads();
        float* zg = z2s + (size_t)bn * CL * CHD;
        for (int i = t; i < 2048; i += 512) {
            int r = i >> 4, c = (i & 15) << 2;
            int gm = (r < 64) ? (m0A + r) : (m0B + r - 64);
            *(float4*)(zg + (size_t)gm * CHD + c) = *(const float4*)&Os[r][c];
        }
    }
}

// ---------------------------------------------------------------------------
// W1_next partial (split-K over l).
// ---------------------------------------------------------------------------
__global__ __launch_bounds__(256) void w1n_part(
    const unsigned short* __restrict__ gz1t, const unsigned short* __restrict__ ktbf,
    const float* __restrict__ lrp, const float* __restrict__ cump,
    float* __restrict__ part) {
    __shared__ __align__(16) unsigned short Ab[128][72];
    __shared__ __align__(16) unsigned short Bb[64][72];
    __shared__ float coefA[128];
    const int ks = blockIdx.x, bn = blockIdx.y, t = threadIdx.x;
    const int lc0 = ks << 7;
    const int wv = t >> 6, lane = t & 63;
    const int lm = lane & 15, lg = lane >> 4;
    const float cum_last = cump[(size_t)bn * CL + CL - 1];
    if (t < 128)
        coefA[t] = lrp[(size_t)bn * CL + lc0 + t] *
                   __expf(cum_last - cump[(size_t)bn * CL + lc0 + t]);
    f32x4 acc[2][4];
#pragma unroll
    for (int i = 0; i < 2; ++i)
#pragma unroll
        for (int j = 0; j < 4; ++j) acc[i][j] = (f32x4){0.f, 0.f, 0.f, 0.f};
    for (int lo = 0; lo < 128; lo += 64) {
        __syncthreads();
        for (int i = t; i < 1024; i += 256) {
            int h = i >> 3, cc = (i & 7) * 8;
            uint4 g = *(const uint4*)(gz1t + ((size_t)bn * CHDH + h) * CL + lc0 + lo + cc);
            unsigned short* gp = (unsigned short*)&g;
            uint4 o;
            o.x = pk2(bf2f(gp[0]) * coefA[lo + cc + 0], bf2f(gp[1]) * coefA[lo + cc + 1]);
            o.y = pk2(bf2f(gp[2]) * coefA[lo + cc + 2], bf2f(gp[3]) * coefA[lo + cc + 3]);
            o.z = pk2(bf2f(gp[4]) * coefA[lo + cc + 4], bf2f(gp[5]) * coefA[lo + cc + 5]);
            o.w = pk2(bf2f(gp[6]) * coefA[lo + cc + 6], bf2f(gp[7]) * coefA[lo + cc + 7]);
            *(uint4*)&Ab[h][cc] = o;
        }
        for (int i = t; i < 512; i += 256) {
            int d = i >> 3, cc = (i & 7) * 8;
            *(uint4*)&Bb[d][cc] =
                *(const uint4*)(ktbf + ((size_t)bn * CHD + d) * CL + lc0 + lo + cc);
        }
        __syncthreads();
#pragma unroll
        for (int mm = 0; mm < 2; ++mm) {
            int m16 = wv * 2 + mm;
#pragma unroll
            for (int n16 = 0; n16 < 4; ++n16)
#pragma unroll
                for (int kk = 0; kk < 2; ++kk) {
                    short8v a = *(const short8v*)&Ab[m16 * 16 + lm][kk * 32 + lg * 8];
                    short8v b = *(const short8v*)&Bb[n16 * 16 + lm][kk * 32 + lg * 8];
                    acc[mm][n16] = MFMA16(a, b, acc[mm][n16]);
                }
        }
    }
    float* og = part + (((size_t)bn * 8 + ks) << 13);
#pragma unroll
    for (int mm = 0; mm < 2; ++mm)
#pragma unroll
        for (int n16 = 0; n16 < 4; ++n16)
#pragma unroll
            for (int r = 0; r < 4; ++r) {
                int h = (wv * 2 + mm) * 16 + lg * 4 + r;
                int d = n16 * 16 + lm;
                og[h * CHD + d] = acc[mm][n16][r];
            }
}

// ---------------------------------------------------------------------------
// W2_next partial (split-K over l).
// ---------------------------------------------------------------------------
__global__ __launch_bounds__(256) void w2n_part(
    const unsigned short* __restrict__ gz2t, const unsigned short* __restrict__ x2t,
    const float* __restrict__ lrp, const float* __restrict__ cump,
    float* __restrict__ part) {
    __shared__ __align__(16) unsigned short Ab[64][72];
    __shared__ __align__(16) unsigned short Bb[128][72];
    __shared__ float coefA[128];
    const int ks = blockIdx.x, bn = blockIdx.y, t = threadIdx.x;
    const int lc0 = ks << 7;
    const int wv = t >> 6, lane = t & 63;
    const int lm = lane & 15, lg = lane >> 4;
    const float cum_last = cump[(size_t)bn * CL + CL - 1];
    if (t < 128)
        coefA[t] = lrp[(size_t)bn * CL + lc0 + t] *
                   __expf(cum_last - cump[(size_t)bn * CL + lc0 + t]);
    f32x4 acc[8];
#pragma unroll
    for (int i = 0; i < 8; ++i) acc[i] = (f32x4){0.f, 0.f, 0.f, 0.f};
    for (int lo = 0; lo < 128; lo += 64) {
        __syncthreads();
        for (int i = t; i < 512; i += 256) {
            int d = i >> 3, cc = (i & 7) * 8;
            uint4 g = *(const uint4*)(gz2t + ((size_t)bn * CHD + d) * CL + lc0 + lo + cc);
            unsigned short* gp = (unsigned short*)&g;
            uint4 o;
            o.x = pk2(bf2f(gp[0]) * coefA[lo + cc + 0], bf2f(gp[1]) * coefA[lo + cc + 1]);
            o.y = pk2(bf2f(gp[2]) * coefA[lo + cc + 2], bf2f(gp[3]) * coefA[lo + cc + 3]);
            o.z = pk2(bf2f(gp[4]) * coefA[lo + cc + 4], bf2f(gp[5]) * coefA[lo + cc + 5]);
            o.w = pk2(bf2f(gp[6]) * coefA[lo + cc + 6], bf2f(gp[7]) * coefA[lo + cc + 7]);
            *(uint4*)&Ab[d][cc] = o;
        }
        for (int i = t; i < 1024; i += 256) {
            int h = i >> 3, cc = (i & 7) * 8;
            *(uint4*)&Bb[h][cc] =
                *(const uint4*)(x2t + ((size_t)bn * CHDH + h) * CL + lc0 + lo + cc);
        }
        __syncthreads();
#pragma unroll
        for (int n16 = 0; n16 < 8; ++n16)
#pragma unroll
            for (int kk = 0; kk < 2; ++kk) {
                short8v a = *(const short8v*)&Ab[wv * 16 + lm][kk * 32 + lg * 8];
                short8v b = *(const short8v*)&Bb[n16 * 16 + lm][kk * 32 + lg * 8];
                acc[n16] = MFMA16(a, b, acc[n16]);
            }
    }
    float* og = part + (((size_t)bn * 8 + ks) << 13);
#pragma unroll
    for (int n16 = 0; n16 < 8; ++n16)
#pragma unroll
        for (int r = 0; r < 4; ++r) {
            int d = wv * 16 + lg * 4 + r;
            int h = n16 * 16 + lm;
            og[d * CHDH + h] = acc[n16][r];
        }
}

// ---------------------------------------------------------------------------
// Reduce partials (fixed order, deterministic).
// ---------------------------------------------------------------------------
__global__ __launch_bounds__(256) void wn_red(
    const float* __restrict__ w1part, const float* __restrict__ w2part,
    const float* __restrict__ W1, const float* __restrict__ W2,
    const float* __restrict__ cump, float* __restrict__ w1n,
    float* __restrict__ w2n) {
    int g = blockIdx.x * 256 + threadIdx.x;
    const bool isw2 = g >= 65536;
    int e = isw2 ? g - 65536 : g;
    int bn = e >> 11, off = e & 2047;
    const float4* part = (const float4*)(isw2 ? w2part : w1part);
    float4 s = {0.f, 0.f, 0.f, 0.f};
#pragma unroll
    for (int ks = 0; ks < 8; ++ks) {
        float4 v = part[(((size_t)bn * 8 + ks) << 11) + off];
        s.x += v.x; s.y += v.y; s.z += v.z; s.w += v.w;
    }
    const float wdcl = __expf(cump[(size_t)bn * CL + CL - 1]);
    float4 w = ((const float4*)((isw2 ? W2 : W1) + ((size_t)bn << 13)))[off];
    float4 o;
    o.x = wdcl * w.x - s.x;
    o.y = wdcl * w.y - s.y;
    o.z = wdcl * w.z - s.z;
    o.w = wdcl * w.w - s.w;
    ((float4*)((isw2 ? w2n : w1n) + ((size_t)bn << 13)))[off] = o;
}

// ---------------------------------------------------------------------------
extern "C" void kernel_launch(void* const* d_in, const int* in_sizes, int n_in,
                              void* d_out, int out_size, void* d_ws, size_t ws_size,
                              hipStream_t stream) {
    (void)in_sizes; (void)n_in; (void)out_size; (void)ws_size;
    const float* x      = (const float*)d_in[0];
    const float* W1     = (const float*)d_in[1];
    const float* W2     = (const float*)d_in[2];
    const float* lblr   = (const float*)d_in[3];
    const float* fclr_w = (const float*)d_in[4];
    const float* fclr_b = (const float*)d_in[5];
    const float* lbwd   = (const float*)d_in[6];
    const float* fcwd_w = (const float*)d_in[7];
    const float* fcwd_b = (const float*)d_in[8];
    const float* qw = (const float*)d_in[9];
    const float* qb = (const float*)d_in[10];
    const float* kw = (const float*)d_in[11];
    const float* kb = (const float*)d_in[12];
    const float* vw = (const float*)d_in[13];
    const float* vb = (const float*)d_in[14];
    const float* ow = (const float*)d_in[15];
    const float* ob = (const float*)d_in[16];

    float* ws = (float*)d_ws;
    const size_t SZ_HD = (size_t)CBN * CL * CHD;
    const size_t SZ_HDH = (size_t)CBN * CL * CHDH;
    float* qh   = ws;
    float* khb  = qh + SZ_HD;
    float* vhb  = khb + SZ_HD;
    float* gz2b = vhb + SZ_HD;
    float* z2sb = gz2b + SZ_HD;
    float* x2b  = z2sb + SZ_HD;
    float* gz1b = x2b + SZ_HDH;
    float* x2qb = gz1b + SZ_HDH;
    float* lrb  = x2qb + SZ_HDH;
    float* cumb = lrb + (size_t)CBN * CL;
    float* wdcb = cumb + (size_t)CBN * CL;
    unsigned short* xbf  = (unsigned short*)(wdcb + (size_t)CBN * CL);
    unsigned short* qwbf = xbf + (size_t)CB * CL * CD;
    unsigned short* kwbf = qwbf + (size_t)CD * CD;
    unsigned short* vwbf = kwbf + (size_t)CD * CD;
    unsigned short* owh  = vwbf + (size_t)CD * CD;
    unsigned short* owl  = owh + (size_t)CD * CD;

    unsigned short* qbf   = (unsigned short*)qh;
    unsigned short* kbf   = qbf + SZ_HD;
    unsigned short* ktbf  = (unsigned short*)khb;
    unsigned short* w1bf  = ktbf + SZ_HD;
    unsigned short* w2bf  = w1bf + (size_t)CBN * CHDH * CHD;
    unsigned short* w2tbf = w2bf + (size_t)CBN * CHDH * CHD;
    unsigned short* gz2t  = (unsigned short*)gz2b;
    unsigned short* x2t   = (unsigned short*)x2b;
    unsigned short* gz1t  = (unsigned short*)gz1b;
    unsigned short* x2q   = (unsigned short*)x2qb;
    unsigned short* x2bf  = x2q + SZ_HDH;
    float* w1part = qh;
    float* w2part = vhb;

    float* outp = (float*)d_out;
    float* w1n = outp + (size_t)CB * CL * CD;
    float* w2n = w1n + (size_t)CBN * CHDH * CHD;

    conv_kernel<<<6912, 256, 0, stream>>>(x, qw, kw, vw, W1, W2, ow, xbf, qwbf, kwbf,
                                          vwbf, w1bf, w2bf, w2tbf, owh, owl);
    qkv_mfma<<<dim3(24, 16), 512, 0, stream>>>(xbf, qwbf, qb, kb, vb, qbf, kbf, ktbf,
                                               vhb);
    lrwd_kernel<<<CB * CL, 64, 0, stream>>>(x, lblr, fclr_w, fclr_b, lbwd, fcwd_w,
                                            fcwd_b, lrb, cumb);
    scan_kernel<<<CBN, 64, 0, stream>>>(cumb, wdcb);
    mlp_mfma<<<dim3(CL / 64, CBN), 256, 0, stream>>>(kbf, vhb, w1bf, w2bf, w2tbf,
                                                     x2bf, x2t, gz1t, gz2t);
    attn1_mfma<<<dim3(8, CBN), 512, 0, stream>>>(qbf, kbf, gz1t, w1bf, lrb, cumb,
                                                 wdcb, x2q);
    w1n_part<<<dim3(8, CBN), 256, 0, stream>>>(gz1t, ktbf, lrb, cumb, w1part);
    w2n_part<<<dim3(8, CBN), 256, 0, stream>>>(gz2t, x2t, lrb, cumb, w2part);
    wn_red<<<512, 256, 0, stream>>>(w1part, w2part, W1, W2, cumb, w1n, w2n);
    attn2_mfma<<<dim3(8, CBN), 512, 0, stream>>>(x2q, x2bf, gz2t, w2bf, lrb, cumb,
                                                 wdcb, z2sb);
    gemm_obf<<<dim3(CD / 64, (CB * CL) / 64), 256, 0, stream>>>(z2sb, owh, owl, ob,
                                                                outp);
}